// Round 6
// baseline (528.578 us; speedup 1.0000x reference)
//
#include <hip/hip_runtime.h>
#include <hip/hip_bf16.h>

#define B 4
#define L 2048
#define D 1024
#define NH 4
#define DK 256
#define CHUNK 32
#define NCH 64
#define BH (B*NH)
// EMA chunking
#define ET 64
#define ENCH (L/ET)
// conv kernel: timesteps per block
#define TB 8

typedef __attribute__((ext_vector_type(8))) __bf16 bf16x8;
typedef __attribute__((ext_vector_type(4))) __bf16 bf16x4;
typedef __attribute__((ext_vector_type(4))) float f32x4;

__device__ inline unsigned short f2bf(float f) {
    union { float f; unsigned u; } v; v.f = f;
    unsigned r = v.u + 0x7fffu + ((v.u >> 16) & 1u);
    return (unsigned short)(r >> 16);
}
__device__ inline float bf2f(unsigned short h) {
    union { unsigned u; float f; } v; v.u = ((unsigned)h) << 16; return v.f;
}
__device__ inline float sigmoidf_(float x) { return 1.0f / (1.0f + __expf(-x)); }
__device__ inline float siluf_(float x) { return x / (1.0f + __expf(-x)); }
// pack 2 f32 -> 2 bf16 in one u32 (RNE), single instruction
__device__ inline unsigned cvt_pk_bf16(float lo, float hi) {
    unsigned r;
    asm("v_cvt_pk_bf16_f32 %0, %1, %2" : "=v"(r) : "v"(lo), "v"(hi));
    return r;
}

#define MFMA16(a, b, c) __builtin_amdgcn_mfma_f32_16x16x32_bf16((a), (b), (c), 0, 0, 0)

// raw barrier: wait only LDS (lgkmcnt(0)), leave global/DMA loads in flight.
// 0xC07F = vmcnt(63) expcnt(7) lgkmcnt(0)
__device__ inline void bar_lds() {
    __builtin_amdgcn_s_waitcnt(0xC07F);
    __builtin_amdgcn_s_barrier();
}

// async global->LDS, 16B per lane; lds dest = wave-uniform base + lane*16
__device__ inline void load_lds16(const unsigned short* g, unsigned short* l) {
    __builtin_amdgcn_global_load_lds(
        (const __attribute__((address_space(1))) unsigned int*)g,
        (__attribute__((address_space(3))) unsigned int*)l, 16, 0, 0);
}

// ---------------- K1: transpose+convert weights: W (K,N) f32 -> WT (N,K) bf16 ----------------
__global__ __launch_bounds__(256) void k_wT(const float* Wq, const float* Wk, const float* Wv,
                                            const float* Wo, unsigned short* wT)
{
    __shared__ float tile[32][33];
    int z = blockIdx.z;
    const float* W = (z == 0) ? Wq : (z == 1) ? Wk : (z == 2) ? Wv : Wo;
    unsigned short* out = wT + (size_t)z * D * D;
    int kt = blockIdx.x * 32, nt = blockIdx.y * 32;
    int tx = threadIdx.x & 31, ty = threadIdx.x >> 5;
#pragma unroll
    for (int i = 0; i < 4; i++)
        tile[ty + 8 * i][tx] = W[(size_t)(kt + ty + 8 * i) * D + nt + tx];
    __syncthreads();
#pragma unroll
    for (int i = 0; i < 4; i++)
        out[(size_t)(nt + ty + 8 * i) * D + kt + tx] = f2bf(tile[tx][ty + 8 * i]);
}

// ---------------- K2: hidden f32 -> bf16 ----------------
__global__ __launch_bounds__(256) void k_cvt(const float* h, unsigned short* hb, int n4)
{
    int i = blockIdx.x * blockDim.x + threadIdx.x;
    int stride = gridDim.x * blockDim.x;
    const float4* h4 = (const float4*)h;
    for (; i < n4; i += stride) {
        float4 v = h4[i];
        ushort4 o;
        o.x = f2bf(v.x); o.y = f2bf(v.y); o.z = f2bf(v.z); o.w = f2bf(v.w);
        *(ushort4*)(hb + 4 * (size_t)i) = o;
    }
}

// ---------------- K3: LDS-staged 128x128 GEMM (m97 structure) ----------------
template<int NTOT, bool OUT_F32>
__global__ __launch_bounds__(256) void k_gemm_lds(const unsigned short* __restrict__ A,
                                                  const unsigned short* __restrict__ BT,
                                                  void* __restrict__ outp)
{
    __shared__ __align__(16) unsigned short As[128 * 32];   // 8 KB
    __shared__ __align__(16) unsigned short Bs[128 * 32];   // 8 KB
    const int K = 1024;
    int tid = threadIdx.x;
    int w = tid >> 6, lane = tid & 63;
    int r16 = lane & 15, quad = lane >> 4;
    int wm = w & 1, wn = w >> 1;
    int bm = blockIdx.x * 128;
    int bn = blockIdx.y * 128;
    int lrow = lane >> 2;            // 0..15
    int lcol = (lane & 3) * 8;       // element col within 32
    f32x4 z4 = {0.f, 0.f, 0.f, 0.f};
    f32x4 acc[4][4];
#pragma unroll
    for (int i = 0; i < 4; i++)
#pragma unroll
        for (int j = 0; j < 4; j++) acc[i][j] = z4;

    for (int kt = 0; kt < K; kt += 32) {
#pragma unroll
        for (int j = 0; j < 2; j++) {
            int r0 = (w * 2 + j) * 16;
            load_lds16(A + (size_t)(bm + r0 + lrow) * K + kt + lcol, &As[r0 * 32]);
            load_lds16(BT + (size_t)(bn + r0 + lrow) * K + kt + lcol, &Bs[r0 * 32]);
        }
        __syncthreads();
        bf16x8 af[4], bf[4];
#pragma unroll
        for (int ms = 0; ms < 4; ms++)
            af[ms] = *(const bf16x8*)&As[(wm * 64 + ms * 16 + r16) * 32 + quad * 8];
#pragma unroll
        for (int ns = 0; ns < 4; ns++)
            bf[ns] = *(const bf16x8*)&Bs[(wn * 64 + ns * 16 + r16) * 32 + quad * 8];
#pragma unroll
        for (int ms = 0; ms < 4; ms++)
#pragma unroll
            for (int ns = 0; ns < 4; ns++)
                acc[ms][ns] = MFMA16(af[ms], bf[ns], acc[ms][ns]);
        __syncthreads();
    }
#pragma unroll
    for (int ms = 0; ms < 4; ms++)
#pragma unroll
        for (int ns = 0; ns < 4; ns++)
#pragma unroll
            for (int r = 0; r < 4; r++) {
                int m = bm + wm * 64 + ms * 16 + quad * 4 + r;
                int n = bn + wn * 64 + ns * 16 + r16;
                if (OUT_F32)
                    ((float*)outp)[(size_t)m * NTOT + n] = acc[ms][ns][r];
                else
                    ((unsigned short*)outp)[(size_t)m * NTOT + n] = f2bf(acc[ms][ns][r]);
            }
}

// ---------------- K4: small projections ----------------
__global__ __launch_bounds__(256) void k_smallproj(const float* hid, const float* Wb, const float* Wd,
                                                   const float* Wm, float* beta, float* gamma, float* xmix)
{
    int wave = threadIdx.x >> 6, lane = threadIdx.x & 63;
    int row = blockIdx.x * 4 + wave;
    const float* hrow = hid + (size_t)row * D;
    float acc[12];
#pragma unroll
    for (int j = 0; j < 12; j++) acc[j] = 0.f;
    for (int i = 0; i < 16; i++) {
        int k = lane + 64 * i;
        float h = hrow[k];
        float4 wb = ((const float4*)Wb)[k];
        float4 wd = ((const float4*)Wd)[k];
        float4 wm = ((const float4*)Wm)[k];
        acc[0] += h * wb.x; acc[1] += h * wb.y; acc[2] += h * wb.z; acc[3] += h * wb.w;
        acc[4] += h * wd.x; acc[5] += h * wd.y; acc[6] += h * wd.z; acc[7] += h * wd.w;
        acc[8] += h * wm.x; acc[9] += h * wm.y; acc[10] += h * wm.z; acc[11] += h * wm.w;
    }
#pragma unroll
    for (int j = 0; j < 12; j++)
        for (int off = 32; off; off >>= 1) acc[j] += __shfl_xor(acc[j], off, 64);
    if (lane < 4) {
        beta[(size_t)row * 4 + lane] = sigmoidf_(acc[lane]);
        gamma[(size_t)row * 4 + lane] = sigmoidf_(acc[4 + lane]);
        xmix[(size_t)row * 4 + lane] = acc[8 + lane];
    }
}

// ---------------- K5 (fused): conv + silu(+silu) + per-head l2norm -> qn/kn bf16; v -> bf16 ----------------
// TB consecutive timesteps per block (one b). Accumulate-on-arrival ring: each row read ONCE.
__global__ __launch_bounds__(256) void k_convnorm(const unsigned short* __restrict__ xqkv,
                                                  const float* __restrict__ cq,
                                                  const float* __restrict__ ck,
                                                  const float* __restrict__ cv,
                                                  unsigned short* __restrict__ qn,
                                                  unsigned short* __restrict__ kn,
                                                  unsigned short* __restrict__ vb)
{
    int blk = blockIdx.x;                 // B*(L/TB) blocks
    int b = blk >> 8;                     // L/TB = 256
    int t0 = (blk & 255) * TB;
    int tid = threadIdx.x;
    int h = tid >> 6, lane = tid & 63;
    int c = tid * 4;

    // conv weights [ch][tap], loaded once per block (L1/L2-resident)
    float wq[4][4], wk[4][4], wv[4][4];
#pragma unroll
    for (int j = 0; j < 4; j++) {
        float4 a = *(const float4*)(cq + (size_t)(c + j) * 4);
        wq[j][0] = a.x; wq[j][1] = a.y; wq[j][2] = a.z; wq[j][3] = a.w;
        float4 d4 = *(const float4*)(ck + (size_t)(c + j) * 4);
        wk[j][0] = d4.x; wk[j][1] = d4.y; wk[j][2] = d4.z; wk[j][3] = d4.w;
        float4 e = *(const float4*)(cv + (size_t)(c + j) * 4);
        wv[j][0] = e.x; wv[j][1] = e.y; wv[j][2] = e.z; wv[j][3] = e.w;
    }

    // accumulator ring [slot][ch]; slot of output t is (t - t0) & 3 (compile-time below)
    float aq[4][4], ak[4][4], av[4][4];
#pragma unroll
    for (int s = 0; s < 4; s++)
#pragma unroll
        for (int j = 0; j < 4; j++) { aq[s][j] = 0.f; ak[s][j] = 0.f; av[s][j] = 0.f; }

    const unsigned short* xb = xqkv + (size_t)(b * L) * (3 * D) + c;

    // prologue: rows t0-3..t0-1, contributions only to outputs >= t0
#pragma unroll
    for (int p = 0; p < 3; p++) {
        int r = t0 - 3 + p;
        if (r >= 0) {                     // block-uniform branch (only first block of each b skips)
            const unsigned short* pp = xb + (size_t)r * (3 * D);
            ushort4 xq = *(const ushort4*)pp;
            ushort4 xk = *(const ushort4*)(pp + D);
            ushort4 xv = *(const ushort4*)(pp + 2 * D);
            float fq[4] = {bf2f(xq.x), bf2f(xq.y), bf2f(xq.z), bf2f(xq.w)};
            float fk[4] = {bf2f(xk.x), bf2f(xk.y), bf2f(xk.z), bf2f(xk.w)};
            float fv[4] = {bf2f(xv.x), bf2f(xv.y), bf2f(xv.z), bf2f(xv.w)};
#pragma unroll
            for (int d = 3 - p; d <= 3; d++) {
                int s = (p + d + 1) & 3;  // ((r+d) - t0) & 3, compile-time
                int kk = 3 - d;           // out[t] += x[r] * w[kk], kk = r-t+3
#pragma unroll
                for (int j = 0; j < 4; j++) {
                    aq[s][j] += wq[j][kk] * fq[j];
                    ak[s][j] += wk[j][kk] * fk[j];
                    av[s][j] += wv[j][kk] * fv[j];
                }
            }
        }
    }

    // stage row t0
    ushort4 sq2[2], sk2[2], sv2[2];
    {
        const unsigned short* pp = xb + (size_t)t0 * (3 * D);
        sq2[0] = *(const ushort4*)pp;
        sk2[0] = *(const ushort4*)(pp + D);
        sv2[0] = *(const ushort4*)(pp + 2 * D);
    }

#pragma unroll
    for (int i = 0; i < TB; i++) {
        // prefetch row t0+i+1 (latency hidden under this iteration's finalize)
        if (i + 1 < TB) {
            const unsigned short* pp = xb + (size_t)(t0 + i + 1) * (3 * D);
            sq2[(i + 1) & 1] = *(const ushort4*)pp;
            sk2[(i + 1) & 1] = *(const ushort4*)(pp + D);
            sv2[(i + 1) & 1] = *(const ushort4*)(pp + 2 * D);
        }
        // accumulate row t0+i into pending outputs t0+i .. t0+i+3
        {
            ushort4 xq = sq2[i & 1], xk = sk2[i & 1], xv = sv2[i & 1];
            float fq[4] = {bf2f(xq.x), bf2f(xq.y), bf2f(xq.z), bf2f(xq.w)};
            float fk[4] = {bf2f(xk.x), bf2f(xk.y), bf2f(xk.z), bf2f(xk.w)};
            float fv[4] = {bf2f(xv.x), bf2f(xv.y), bf2f(xv.z), bf2f(xv.w)};
#pragma unroll
            for (int d = 0; d < 4; d++) {
                if (i + d < TB) {         // compile-time: skip contributions to outputs beyond block
                    int s = (i + d) & 3;
                    int kk = 3 - d;
#pragma unroll
                    for (int j = 0; j < 4; j++) {
                        aq[s][j] += wq[j][kk] * fq[j];
                        ak[s][j] += wk[j][kk] * fk[j];
                        av[s][j] += wv[j][kk] * fv[j];
                    }
                }
            }
        }
        // finalize output t = t0+i from slot i&3
        {
            const int s = i & 3;
            float rq[4], rk[4], rv[4];
#pragma unroll
            for (int j = 0; j < 4; j++) {
                rq[j] = siluf_(siluf_(aq[s][j]));
                rk[j] = siluf_(siluf_(ak[s][j]));
                rv[j] = siluf_(av[s][j]);
            }
            float sqs = rq[0] * rq[0] + rq[1] * rq[1] + rq[2] * rq[2] + rq[3] * rq[3];
            float sks = rk[0] * rk[0] + rk[1] * rk[1] + rk[2] * rk[2] + rk[3] * rk[3];
            for (int off = 32; off; off >>= 1) {
                sqs += __shfl_xor(sqs, off, 64);
                sks += __shfl_xor(sks, off, 64);
            }
            float qs = rsqrtf(sqs + 1e-6f), ks = rsqrtf(sks + 1e-6f);
            int t = t0 + i;
            size_t oidx = ((size_t)(b * NH + h) * L + t) * DK + lane * 4;
            ushort4 oq, ok, ov;
            oq.x = f2bf(rq[0] * qs); oq.y = f2bf(rq[1] * qs); oq.z = f2bf(rq[2] * qs); oq.w = f2bf(rq[3] * qs);
            ok.x = f2bf(rk[0] * ks); ok.y = f2bf(rk[1] * ks); ok.z = f2bf(rk[2] * ks); ok.w = f2bf(rk[3] * ks);
            ov.x = f2bf(rv[0]); ov.y = f2bf(rv[1]); ov.z = f2bf(rv[2]); ov.w = f2bf(rv[3]);
            *(ushort4*)(qn + oidx) = oq;
            *(ushort4*)(kn + oidx) = ok;
            *(ushort4*)(vb + (size_t)(b * L + t) * D + c) = ov;
            // reset slot for output t+4 (first contribution arrives next iteration)
            if (i + 4 < TB) {
#pragma unroll
                for (int j = 0; j < 4; j++) { aq[s][j] = 0.f; ak[s][j] = 0.f; av[s][j] = 0.f; }
            }
        }
    }
}

// ---------------- K6: mix conv + silu ----------------
__global__ __launch_bounds__(256) void k_convmix(const float* xmix, const float* cmix, float* mixinp)
{
    int idx = blockIdx.x * 256 + threadIdx.x;   // < B*L*NH
    int h = idx & 3;
    int t = (idx >> 2) & (L - 1);
    int b = idx >> 13;
    float acc = 0.f;
#pragma unroll
    for (int kk = 0; kk < 4; kk++) {
        int tt = t - 3 + kk;
        if (tt >= 0) acc += cmix[h * 4 + kk] * xmix[((size_t)(b * L + tt) << 2) + h];
    }
    mixinp[idx] = siluf_(acc);
}

// ---------------- K7b: per-(bh,chunk) delta-rule precompute (MFMA version) ----------------
#define KTS 40   // LDS row stride in shorts: 80B (16B-aligned), dword stride 20 -> 2-way banks (free)
__global__ __launch_bounds__(256) void k_delta_pre(const unsigned short* qn, const unsigned short* kn,
                                                   const unsigned short* vb, const float* beta,
                                                   unsigned short* wneg, unsigned short* knT,
                                                   unsigned short* attnb, float* u)
{
    __shared__ __align__(16) unsigned short kTl[256 * KTS]; // k^T bf16 [dk][t]
    __shared__ __align__(16) unsigned short vTl[256 * KTS]; // v^T bf16 [dk][t]
    __shared__ __align__(16) unsigned short T2b[32 * KTS];  // T2 bf16 [t][t']
    __shared__ float Gs[32 * 33];
    int bx = blockIdx.x;
    int bh = bx >> 6, ch = bx & 63;
    int b = bh >> 2, h = bh & 3;
    int t0 = ch * 32;
    int tid = threadIdx.x;
    int w = tid >> 6, lane = tid & 63;
    int r16 = lane & 15, quad = lane >> 4;
    size_t rowbase = (size_t)(bh * L + t0);
    f32x4 z4 = {0.f, 0.f, 0.f, 0.f};

    // ---- phase A: MFMA G/QK tiles
    if (w < 3) {
        int mi = (w == 0) ? 0 : 1;
        int ni = (w == 2) ? 1 : 0;
        const unsigned short* krm = kn + (rowbase + mi * 16 + r16) * DK;
        const unsigned short* krn = kn + (rowbase + ni * 16 + r16) * DK;
        const unsigned short* qrm = qn + (rowbase + mi * 16 + r16) * DK;
        f32x4 g = z4, qk = z4;
#pragma unroll
        for (int kt = 0; kt < 8; kt++) {
            bf16x8 a  = *(const bf16x8*)(krm + kt * 32 + quad * 8);
            bf16x8 bb = *(const bf16x8*)(krn + kt * 32 + quad * 8);
            bf16x8 qa = *(const bf16x8*)(qrm + kt * 32 + quad * 8);
            g  = MFMA16(a, bb, g);
            qk = MFMA16(qa, bb, qk);
        }
#pragma unroll
        for (int r = 0; r < 4; r++) {
            int i = mi * 16 + quad * 4 + r, j = ni * 16 + r16;
            Gs[i * 33 + j] = g[r];
            attnb[(size_t)(bh * 64 + ch) * 1024 + i * 32 + j] =
                (j <= i) ? f2bf(qk[r]) : (unsigned short)0;
        }
    } else {
        // strictly-upper QK tile (0,1) is all zero
#pragma unroll
        for (int r = 0; r < 4; r++) {
            int i = quad * 4 + r, j = 16 + r16;
            attnb[(size_t)(bh * 64 + ch) * 1024 + i * 32 + j] = 0;
        }
    }
    // ---- phase A2 (all threads): transpose k, v (both bf16) into LDS
    {
        int t = tid & 31, c0 = (tid >> 5) * 32;
        const unsigned short* krow = kn + (rowbase + t) * DK + c0;
        const unsigned short* vrow = vb + ((size_t)(b * L + t0 + t)) * D + h * DK + c0;
#pragma unroll
        for (int j = 0; j < 32; j += 4) {
            ushort4 kv = *(const ushort4*)(krow + j);
            ushort4 vv = *(const ushort4*)(vrow + j);
            kTl[(c0 + j + 0) * KTS + t] = kv.x;
            kTl[(c0 + j + 1) * KTS + t] = kv.y;
            kTl[(c0 + j + 2) * KTS + t] = kv.z;
            kTl[(c0 + j + 3) * KTS + t] = kv.w;
            vTl[(c0 + j + 0) * KTS + t] = vv.x;
            vTl[(c0 + j + 1) * KTS + t] = vv.y;
            vTl[(c0 + j + 2) * KTS + t] = vv.z;
            vTl[(c0 + j + 3) * KTS + t] = vv.w;
        }
    }
    __syncthreads();

    // ---- phase B
    if (w == 0) {
        int c = lane & 31;
        float rr[32];
#pragma unroll
        for (int j = 0; j < 32; j++) rr[j] = Gs[j * 33 + c];
        // Row 0 of the strict-lower T is empty: must be zero.
        rr[0] = 0.f;
        float bc = beta[(size_t)(b * L + t0 + c) * NH + h];
#pragma unroll
        for (int i = 1; i < 32; i++) {
            float bi = __shfl(bc, i, 64);
            float s = -bi * rr[i];
#pragma unroll
            for (int j = 1; j < i; j++) {
                float aij = -bi * __shfl(rr[i], j, 64);
                s += aij * ((c < j) ? rr[j] : 0.f);
            }
            rr[i] = (c < i) ? s : 0.f;
        }
        if (lane < 32) {
#pragma unroll
            for (int i = 0; i < 32; i++) {
                float val = (rr[i] + ((i == c) ? 1.f : 0.f)) * bc;
                T2b[i * KTS + c] = f2bf(val);
            }
        }
    } else {
        int idx = tid - 64;
        for (int rowc = idx; rowc < 256; rowc += 192) {
            unsigned short* kT = knT + ((size_t)(bh * 64 + ch) * DK + rowc) * 32;
#pragma unroll
            for (int seg = 0; seg < 4; seg++) {
                uint4 d = *(const uint4*)&kTl[rowc * KTS + seg * 8];
                *(uint4*)(kT + seg * 8) = d;
            }
        }
    }
    __syncthreads();

    // ---- phase C: u = T2@v (f32 out), wneg = -(T2@k) (bf16 out)
#pragma unroll
    for (int mt = 0; mt < 2; mt++) {
        bf16x8 ta = *(const bf16x8*)&T2b[(mt * 16 + r16) * KTS + quad * 8];
#pragma unroll
        for (int nt2 = 0; nt2 < 4; nt2++) {
            int nt = w * 4 + nt2;
            bf16x8 vb2 = *(const bf16x8*)&vTl[(nt * 16 + r16) * KTS + quad * 8];
            bf16x8 kb = *(const bf16x8*)&kTl[(nt * 16 + r16) * KTS + quad * 8];
            f32x4 uu = MFMA16(ta, vb2, z4);
            f32x4 ww = MFMA16(ta, kb, z4);
            float* ug = u + (rowbase + mt * 16 + quad * 4) * DK + nt * 16 + r16;
            unsigned short* wg = wneg + (rowbase + mt * 16 + quad * 4) * DK + nt * 16 + r16;
#pragma unroll
            for (int r = 0; r < 4; r++) {
                ug[(size_t)r * DK] = uu[r];
                wg[(size_t)r * DK] = f2bf(-ww[r]);
            }
        }
    }
}

// ---------------- K8a: EMA local scan (bf16 v input) ----------------
__global__ __launch_bounds__(256) void k_ema_local(const unsigned short* v, const float* gamma,
                                                   float* ema_local, float* Acum,
                                                   float* s_end, float* Pchunk)
{
    __shared__ float gsh[ET];
    int blk = blockIdx.x;
    int bh = blk >> 5;
    int ch = blk & (ENCH - 1);
    int b = bh >> 2, h = bh & 3;
    int c = threadIdx.x;
    int t0 = ch * ET;
    if (c < ET) gsh[c] = gamma[(size_t)(b * L + t0 + c) * NH + h];
    __syncthreads();
    const unsigned short* vg = v + (size_t)(b * L + t0) * D + h * DK + c;
    float* eg = ema_local + (size_t)(b * L + t0) * D + h * DK + c;
    float* Ag = Acum + (size_t)bh * L + t0;
    float s = 0.f;
    float A = 1.f;
#pragma unroll 8
    for (int i = 0; i < ET; i++) {
        float g = gsh[i];
        s = g * s + (1.f - g) * bf2f(vg[(size_t)i * D]);
        A *= g;
        eg[(size_t)i * D] = s;
        if (c == 0) Ag[i] = A;
    }
    s_end[((size_t)bh * ENCH + ch) * DK + c] = s;
    if (c == 0) Pchunk[(size_t)bh * ENCH + ch] = A;
}

// ---------------- K8b: EMA carry scan ----------------
__global__ __launch_bounds__(256) void k_ema_carry(const float* s_end, const float* Pchunk, float* S_in)
{
    int bh = blockIdx.x;
    int c = threadIdx.x;
    float S = 0.f;
    for (int ch = 0; ch < ENCH; ch++) {
        S_in[((size_t)bh * ENCH + ch) * DK + c] = S;
        float P = Pchunk[(size_t)bh * ENCH + ch];
        S = P * S + s_end[((size_t)bh * ENCH + ch) * DK + c];
    }
}

// ---------------- K9: sequential inter-chunk scan (single wave + DMA-staged operands) ----------------
// One 64-lane wave per (bh, 16 dv-cols); grid 16x16 = 256 blocks (1/CU).
// Full S (256dk x 16c) in 16 f32x4 accumulators. ZERO barriers: all LDS ordering is
// same-wave lgkmcnt. q/w/kT tiles for chunk ch+1 are DMA'd (global_load_lds, zero VGPR
// cost -> un-de-schedulable) into double-buffered LDS; one vmcnt(0) per chunk drains
// loads issued a full chunk (~1000cy) earlier => ~free. q/w source-XOR-swizzled
// (involution col16 ^= row&7) for conflict-free b128 reads; kT layout naturally uniform.
// NOTE (R5 bug, fixed): kT DMA dest stride is seg*512 SHORTS (1024B per 64-lane DMA),
// not seg*1024 — the latter overflowed skT and clobbered st/uat -> NaN.
#define STS 280   // st row stride in shorts (dword stride 140 = 12 mod 32 -> ~2-way)
#define USTR 40   // uat row stride in shorts
__global__ __launch_bounds__(64, 1) void k_scan(const unsigned short* __restrict__ qn,
                                                const unsigned short* __restrict__ wneg,
                                                const unsigned short* __restrict__ knT,
                                                const unsigned short* __restrict__ attnb,
                                                const float* __restrict__ u, float* __restrict__ od)
{
    __shared__ __align__(16) unsigned short sq[2][32 * 256];   // staged q   (16KB x2)
    __shared__ __align__(16) unsigned short sw[2][32 * 256];   // staged w   (16KB x2)
    __shared__ __align__(16) unsigned short skT[2][256 * 32];  // staged kT  (16KB x2)
    __shared__ __align__(16) unsigned short st[16 * STS];      // S^T bf16 [c][dk]
    __shared__ __align__(16) unsigned short uat[16 * USTR];    // u_adj^T bf16 [c][t]
    int bh = blockIdx.x;
    int tile = blockIdx.y;      // 0..15, 16 dv-cols each
    int b = bh >> 2, h = bh & 3;
    int lane = threadIdx.x;     // 0..63
    int n = lane & 15, q = lane >> 4;
    int cbase = tile * 16;
    f32x4 z4 = {0.f, 0.f, 0.f, 0.f};
    // Sacc[i]: rows 16i+q*4+r, col cbase+n
    f32x4 Sacc[16];
#pragma unroll
    for (int i = 0; i < 16; i++) Sacc[i] = z4;

    const unsigned short* qb = qn + (size_t)bh * L * DK;
    const unsigned short* wb = wneg + (size_t)bh * L * DK;
    const float* ub = u + (size_t)bh * L * DK;
    const unsigned short* kTbase = knT + (size_t)bh * 64 * DK * 32;
    const unsigned short* atbase = attnb + (size_t)bh * 64 * 1024;

    int hl = lane >> 5, cc = lane & 31;    // q/w DMA: 2 rows per seg
    // DMA chunk ch's q/w (src-swizzled) and kT (linear) into buffer p. 48 instrs, 0 VGPR.
    auto stage = [&](int ch, int p) {
        const unsigned short* qsrc = qb + (size_t)ch * 32 * DK;
        const unsigned short* wsrc = wb + (size_t)ch * 32 * DK;
        const unsigned short* ksrc = kTbase + (size_t)ch * DK * 32;
#pragma unroll
        for (int seg = 0; seg < 16; seg++) {
            int row = seg * 2 + hl;
            int scol = cc ^ (row & 7);
            load_lds16(qsrc + (size_t)row * DK + scol * 8, sq[p] + seg * 512);
            load_lds16(wsrc + (size_t)row * DK + scol * 8, sw[p] + seg * 512);
            // kT: 16 rows (16 rows * 32 shorts = 512 shorts = 1024B) per seg; per-lane
            // offset lane*8 shorts == (lane>>2)*32 + (lane&3)*8 -> linear row-major copy.
            load_lds16(ksrc + (size_t)seg * 512 + lane * 8 - lane * 8 + (size_t)(seg * 16 + (lane >> 2)) * 32 + (lane & 3) * 8 - (size_t)seg * 512, skT[p] + seg * 512);
        }
    };

    f32x4 uB2[2][2];
    auto loadu = [&](int ch, int p) {
#pragma unroll
        for (int mt = 0; mt < 2; mt++) {
            const float* up = ub + (size_t)(ch * 32 + 16 * mt + q * 4) * DK + cbase + n;
            f32x4 a; a[0] = up[0]; a[1] = up[DK]; a[2] = up[2 * DK]; a[3] = up[3 * DK];
            uB2[p][mt] = a;
        }
    };
    bf16x8 af2[2][2];
    auto loadaf = [&](int ch, int p) {
#pragma unroll
        for (int mt = 0; mt < 2; mt++)
            af2[p][mt] = *(const bf16x8*)(atbase + (size_t)ch * 1024 + (16 * mt + n) * 32 + q * 8);
    };

    stage(0, 0); loadu(0, 0); loadaf(0, 0);

    int rsw = n & 7;
    // body with COMPILE-TIME par so uB2/af2 index statically (registers, not scratch)
    auto body = [&](int ch, int par) {
        int t0 = ch * 32;
        // (0) drain prev chunk's DMA/loads (issued a full chunk ago), then issue next.
        asm volatile("s_waitcnt vmcnt(0)" ::: "memory");
        if (ch + 1 < NCH) {
            stage(ch + 1, par ^ 1);
            loadu(ch + 1, par ^ 1);
            loadaf(ch + 1, par ^ 1);
        }
        // (A) pack S -> st (same-wave; lgkmcnt orders the reads below)
#pragma unroll
        for (int i = 0; i < 16; i++) {
            uint2 pk2;
            pk2.x = cvt_pk_bf16(Sacc[i][0], Sacc[i][1]);
            pk2.y = cvt_pk_bf16(Sacc[i][2], Sacc[i][3]);
            *(uint2*)&st[n * STS + i * 16 + q * 4] = pk2;
        }
        // (C) au = u + wneg@S, ao = q@S for both t-halves (even/odd chain split)
        f32x4 auE[2], auO[2], aoE[2], aoO[2];
#pragma unroll
        for (int mt = 0; mt < 2; mt++) {
            auE[mt] = uB2[par][mt]; auO[mt] = z4; aoE[mt] = z4; aoO[mt] = z4;
        }
#pragma unroll
        for (int kt = 0; kt < 8; kt += 2) {
            bf16x8 s0 = *(const bf16x8*)&st[n * STS + (kt + 0) * 32 + q * 8];
            bf16x8 s1 = *(const bf16x8*)&st[n * STS + (kt + 1) * 32 + q * 8];
#pragma unroll
            for (int mt = 0; mt < 2; mt++) {
                int rowoff = (16 * mt + n) * 256;
                bf16x8 w0 = *(const bf16x8*)&sw[par][rowoff + (((kt + 0) * 4 + q) ^ rsw) * 8];
                bf16x8 q0 = *(const bf16x8*)&sq[par][rowoff + (((kt + 0) * 4 + q) ^ rsw) * 8];
                bf16x8 w1 = *(const bf16x8*)&sw[par][rowoff + (((kt + 1) * 4 + q) ^ rsw) * 8];
                bf16x8 q1 = *(const bf16x8*)&sq[par][rowoff + (((kt + 1) * 4 + q) ^ rsw) * 8];
                auE[mt] = MFMA16(w0, s0, auE[mt]);
                aoE[mt] = MFMA16(q0, s0, aoE[mt]);
                auO[mt] = MFMA16(w1, s1, auO[mt]);
                aoO[mt] = MFMA16(q1, s1, aoO[mt]);
            }
        }
        // (D) u_adj -> uat (transpose bounce, same-wave)
#pragma unroll
        for (int mt = 0; mt < 2; mt++) {
            f32x4 au = auE[mt] + auO[mt];
            uint2 pu;
            pu.x = cvt_pk_bf16(au[0], au[1]);
            pu.y = cvt_pk_bf16(au[2], au[3]);
            *(uint2*)&uat[n * USTR + 16 * mt + q * 4] = pu;
        }
        bf16x8 uf = *(const bf16x8*)&uat[n * USTR + q * 8];
        // (F) o = q@S + attn@u_adj ; store
#pragma unroll
        for (int mt = 0; mt < 2; mt++) {
            f32x4 ao = aoE[mt] + aoO[mt];
            ao = MFMA16(af2[par][mt], uf, ao);
            float* op = od + (size_t)(b * L + t0 + 16 * mt + q * 4) * D + h * DK + cbase + n;
            op[0] = ao[0]; op[D] = ao[1]; op[2 * D] = ao[2]; op[3 * D] = ao[3];
        }
        // (G) S += kT @ u_adj (16 independent MFMAs, kT frags streamed from staged LDS)
#pragma unroll
        for (int i = 0; i < 16; i++) {
            bf16x8 kfi = *(const bf16x8*)&skT[par][(i * 16 + n) * 32 + q * 8];
            Sacc[i] = MFMA16(kfi, uf, Sacc[i]);
        }
    };

    for (int ch2 = 0; ch2 < NCH; ch2 += 2) {
        body(ch2, 0);
        body(ch2 + 1, 1);
    }
}

// ---------------- K10: mix + EMA fix-up + per-head RMS norm -> bf16 ----------------
__global__ __launch_bounds__(256) void k_mixrms(const float* od, const float* ema_local,
                                                const float* Acum, const float* S_in,
                                                const float* mixinp,
                                                const float* mix_bias, const float* rms_w,
                                                unsigned short* onorm)
{
    int row = blockIdx.x;       // b*L + t
    int tid = threadIdx.x;
    int h = tid >> 6, lane = tid & 63;
    int b = row >> 11, t = row & (L - 1);
    int bh = b * NH + h;
    int ch = t >> 6;            // ET = 64
    float m = sigmoidf_(mixinp[(size_t)row * NH + h] + mix_bias[h]);
    int c = tid * 4;
    float A = Acum[(size_t)bh * L + t];
    float4 sin4 = *(const float4*)(S_in + ((size_t)bh * ENCH + ch) * DK + (c & (DK - 1)));
    float4 o = *(const float4*)(od + (size_t)row * D + c);
    float4 e = *(const float4*)(ema_local + (size_t)row * D + c);
    e.x += A * sin4.x; e.y += A * sin4.y; e.z += A * sin4.z; e.w += A * sin4.w;
    float x0 = o.x + m * (e.x - o.x);
    float x1 = o.y + m * (e.y - o.y);
    float x2 = o.z + m * (e.z - o.z);
    float x3 = o.w + m * (e.w - o.w);
    float ss = x0 * x0 + x1 * x1 + x2 * x2 + x3 * x3;
    for (int off = 32; off; off >>= 1) ss += __shfl_xor(ss, off, 64);
    float scale = rsqrtf(ss * (1.0f / 256.0f) + 1e-5f);
    float4 w = *(const float4*)(rms_w + lane * 4);
    uint2 p;
    p.x = f2bf(x0 * scale * w.x) | ((unsigned)f2bf(x1 * scale * w.y) << 16);
    p.y = f2bf(x2 * scale * w.z) | ((unsigned)f2bf(x3 * scale * w.w) << 16);
    *(uint2*)(onorm + (size_t)row * D + c) = p;
}

extern "C" void kernel_launch(void* const* d_in, const int* in_sizes, int n_in,
                              void* d_out, int out_size, void* d_ws, size_t ws_size,
                              hipStream_t stream)
{
    (void)in_sizes; (void)n_in; (void)out_size; (void)ws_size;
    const float* hidden   = (const float*)d_in[0];
    const float* Wq       = (const float*)d_in[1];
    const float* Wk       = (const float*)d_in[2];
    const float* Wv       = (const float*)d_in[3];
    const float* conv_q   = (const float*)d_in[4];
    const float* conv_k   = (const float*)d_in[5];
    const float* conv_v   = (const float*)d_in[6];
    const float* Wb       = (const float*)d_in[7];
    const float* Wdec     = (const float*)d_in[8];
    const float* Wmix     = (const float*)d_in[9];
    const float* conv_mix = (const float*)d_in[10];
    const float* mix_bias = (const float*)d_in[11];
    const float* rms_w    = (const float*)d_in[12];
    const float* Wo       = (const float*)d_in[13];
    float* out = (float*)d_out;

    char* ws = (char*)d_ws;
    size_t off = 0;
    auto alloc = [&](size_t bytes) -> char* {
        char* p = ws + off;
        off += (bytes + 255) & ~(size_t)255;
        return p;
    };
    unsigned short* wT    = (unsigned short*)alloc((size_t)4 * D * D * 2);
    unsigned short* hidB  = (unsigned short*)alloc((size_t)B * L * D * 2);
    unsigned short* xqkv  = (unsigned short*)alloc((size_t)B * L * 3 * D * 2); // slices 1,2 reused as wneg/knT
    float* beta   = (float*)alloc((size_t)B * L * NH * 4);
    float* gamma  = (float*)alloc((size_t)B * L * NH * 4);
    float* xmix   = (float*)alloc((size_t)B * L * NH * 4);
    float* mixinp = (float*)alloc((size_t)B * L * NH * 4);
    float* qbuf   = (float*)alloc((size_t)B * L * D * 4);   // ema_local
    float* kbuf   = (float*)alloc((size_t)B * L * D * 4);   // od
    unsigned short* vb = (unsigned short*)alloc((size_t)B * L * D * 2);  // v bf16
    float* u      = (float*)alloc((size_t)B * L * D * 4);
    unsigned short* attnb = (unsigned short*)alloc((size_t)BH * NCH * CHUNK * CHUNK * 2);
    unsigned short* onorm = (unsigned short*)alloc((size_t)B * L * D * 2);
    unsigned short* kn    = (unsigned short*)alloc((size_t)B * L * D * 2);
    unsigned short* qn    = (unsigned short*)alloc((size_t)B * L * D * 2);
    float* Acum   = (float*)alloc((size_t)BH * L * 4);
    float* s_end  = (float*)alloc((size_t)BH * ENCH * DK * 4);
    float* Pchunk = (float*)alloc((size_t)BH * ENCH * 4);
    float* S_in   = (float*)alloc((size_t)BH * ENCH * DK * 4);

    unsigned short* wneg = xqkv + (size_t)B * L * D;       // xqkv dead after k_convnorm
    unsigned short* knT  = xqkv + (size_t)2 * B * L * D;
    float* ema_local = qbuf;
    float* od  = kbuf;

    k_wT<<<dim3(32, 32, 4), 256, 0, stream>>>(Wq, Wk, Wv, Wo, wT);
    k_cvt<<<dim3(2048), 256, 0, stream>>>(hidden, hidB, B * L * D / 4);
    k_gemm_lds<3 * D, false><<<dim3(64, 24), 256, 0, stream>>>(hidB, wT, xqkv);
    k_smallproj<<<dim3(B * L / 4), 256, 0, stream>>>(hidden, Wb, Wdec, Wmix, beta, gamma, xmix);
    k_convnorm<<<dim3(B * L / TB), 256, 0, stream>>>(xqkv, conv_q, conv_k, conv_v, qn, kn, vb);
    k_convmix<<<dim3(B * L * NH / 256), 256, 0, stream>>>(xmix, conv_mix, mixinp);
    k_delta_pre<<<dim3(BH * NCH), 256, 0, stream>>>(qn, kn, vb, beta, wneg, knT, attnb, u);
    k_ema_local<<<dim3(BH * ENCH), 256, 0, stream>>>(vb, gamma, ema_local, Acum, s_end, Pchunk);
    k_ema_carry<<<dim3(BH), 256, 0, stream>>>(s_end, Pchunk, S_in);
    k_scan<<<dim3(16, 16), 64, 0, stream>>>(qn, wneg, knT, attnb, u, od);
    k_mixrms<<<dim3(B * L), 256, 0, stream>>>(od, ema_local, Acum, S_in, mixinp, mix_bias, rms_w, onorm);
    k_gemm_lds<D, true><<<dim3(64, 8), 256, 0, stream>>>(onorm, wT + (size_t)3 * D * D, out);
}

// Round 7
// 459.527 us; speedup vs baseline: 1.1503x; 1.1503x over previous
//
#include <hip/hip_runtime.h>
#include <hip/hip_bf16.h>

#define B 4
#define L 2048
#define D 1024
#define NH 4
#define DK 256
#define CHUNK 32
#define NCH 64
#define BH (B*NH)
// EMA chunking
#define ET 64
#define ENCH (L/ET)
// conv kernel: timesteps per block
#define TB 16

typedef __attribute__((ext_vector_type(8))) __bf16 bf16x8;
typedef __attribute__((ext_vector_type(4))) __bf16 bf16x4;
typedef __attribute__((ext_vector_type(4))) float f32x4;

__device__ inline unsigned short f2bf(float f) {
    union { float f; unsigned u; } v; v.f = f;
    unsigned r = v.u + 0x7fffu + ((v.u >> 16) & 1u);
    return (unsigned short)(r >> 16);
}
__device__ inline float bf2f(unsigned short h) {
    union { unsigned u; float f; } v; v.u = ((unsigned)h) << 16; return v.f;
}
__device__ inline float sigmoidf_(float x) { return 1.0f / (1.0f + __expf(-x)); }
__device__ inline float siluf_(float x) { return x / (1.0f + __expf(-x)); }

#define MFMA16(a, b, c) __builtin_amdgcn_mfma_f32_16x16x32_bf16((a), (b), (c), 0, 0, 0)

// raw barrier: wait only LDS (lgkmcnt(0)), leave global loads in flight.
// 0xC07F = vmcnt(63) expcnt(7) lgkmcnt(0)
__device__ inline void bar_lds() {
    __builtin_amdgcn_s_waitcnt(0xC07F);
    __builtin_amdgcn_s_barrier();
}

// async global->LDS, 16B per lane; lds dest = wave-uniform base + lane*16
__device__ inline void load_lds16(const unsigned short* g, unsigned short* l) {
    __builtin_amdgcn_global_load_lds(
        (const __attribute__((address_space(1))) unsigned int*)g,
        (__attribute__((address_space(3))) unsigned int*)l, 16, 0, 0);
}

// ---------------- K1: transpose+convert weights: W (K,N) f32 -> WT (N,K) bf16 ----------------
__global__ __launch_bounds__(256) void k_wT(const float* Wq, const float* Wk, const float* Wv,
                                            const float* Wo, unsigned short* wT)
{
    __shared__ float tile[32][33];
    int z = blockIdx.z;
    const float* W = (z == 0) ? Wq : (z == 1) ? Wk : (z == 2) ? Wv : Wo;
    unsigned short* out = wT + (size_t)z * D * D;
    int kt = blockIdx.x * 32, nt = blockIdx.y * 32;
    int tx = threadIdx.x & 31, ty = threadIdx.x >> 5;
#pragma unroll
    for (int i = 0; i < 4; i++)
        tile[ty + 8 * i][tx] = W[(size_t)(kt + ty + 8 * i) * D + nt + tx];
    __syncthreads();
#pragma unroll
    for (int i = 0; i < 4; i++)
        out[(size_t)(nt + ty + 8 * i) * D + kt + tx] = f2bf(tile[tx][ty + 8 * i]);
}

// ---------------- K2: hidden f32 -> bf16 ----------------
__global__ __launch_bounds__(256) void k_cvt(const float* h, unsigned short* hb, int n4)
{
    int i = blockIdx.x * blockDim.x + threadIdx.x;
    int stride = gridDim.x * blockDim.x;
    const float4* h4 = (const float4*)h;
    for (; i < n4; i += stride) {
        float4 v = h4[i];
        ushort4 o;
        o.x = f2bf(v.x); o.y = f2bf(v.y); o.z = f2bf(v.z); o.w = f2bf(v.w);
        *(ushort4*)(hb + 4 * (size_t)i) = o;
    }
}

// ---------------- K3: LDS-staged 128x128 GEMM (m97 structure) ----------------
template<int NTOT, bool OUT_F32>
__global__ __launch_bounds__(256) void k_gemm_lds(const unsigned short* __restrict__ A,
                                                  const unsigned short* __restrict__ BT,
                                                  void* __restrict__ outp)
{
    __shared__ __align__(16) unsigned short As[128 * 32];   // 8 KB
    __shared__ __align__(16) unsigned short Bs[128 * 32];   // 8 KB
    const int K = 1024;
    int tid = threadIdx.x;
    int w = tid >> 6, lane = tid & 63;
    int r16 = lane & 15, quad = lane >> 4;
    int wm = w & 1, wn = w >> 1;
    int bm = blockIdx.x * 128;
    int bn = blockIdx.y * 128;
    int lrow = lane >> 2;            // 0..15
    int lcol = (lane & 3) * 8;       // element col within 32
    f32x4 z4 = {0.f, 0.f, 0.f, 0.f};
    f32x4 acc[4][4];
#pragma unroll
    for (int i = 0; i < 4; i++)
#pragma unroll
        for (int j = 0; j < 4; j++) acc[i][j] = z4;

    for (int kt = 0; kt < K; kt += 32) {
#pragma unroll
        for (int j = 0; j < 2; j++) {
            int r0 = (w * 2 + j) * 16;
            load_lds16(A + (size_t)(bm + r0 + lrow) * K + kt + lcol, &As[r0 * 32]);
            load_lds16(BT + (size_t)(bn + r0 + lrow) * K + kt + lcol, &Bs[r0 * 32]);
        }
        __syncthreads();
        bf16x8 af[4], bf[4];
#pragma unroll
        for (int ms = 0; ms < 4; ms++)
            af[ms] = *(const bf16x8*)&As[(wm * 64 + ms * 16 + r16) * 32 + quad * 8];
#pragma unroll
        for (int ns = 0; ns < 4; ns++)
            bf[ns] = *(const bf16x8*)&Bs[(wn * 64 + ns * 16 + r16) * 32 + quad * 8];
#pragma unroll
        for (int ms = 0; ms < 4; ms++)
#pragma unroll
            for (int ns = 0; ns < 4; ns++)
                acc[ms][ns] = MFMA16(af[ms], bf[ns], acc[ms][ns]);
        __syncthreads();
    }
#pragma unroll
    for (int ms = 0; ms < 4; ms++)
#pragma unroll
        for (int ns = 0; ns < 4; ns++)
#pragma unroll
            for (int r = 0; r < 4; r++) {
                int m = bm + wm * 64 + ms * 16 + quad * 4 + r;
                int n = bn + wn * 64 + ns * 16 + r16;
                if (OUT_F32)
                    ((float*)outp)[(size_t)m * NTOT + n] = acc[ms][ns][r];
                else
                    ((unsigned short*)outp)[(size_t)m * NTOT + n] = f2bf(acc[ms][ns][r]);
            }
}

// ---------------- K4: small projections ----------------
__global__ __launch_bounds__(256) void k_smallproj(const float* hid, const float* Wb, const float* Wd,
                                                   const float* Wm, float* beta, float* gamma, float* xmix)
{
    int wave = threadIdx.x >> 6, lane = threadIdx.x & 63;
    int row = blockIdx.x * 4 + wave;
    const float* hrow = hid + (size_t)row * D;
    float acc[12];
#pragma unroll
    for (int j = 0; j < 12; j++) acc[j] = 0.f;
    for (int i = 0; i < 16; i++) {
        int k = lane + 64 * i;
        float h = hrow[k];
        float4 wb = ((const float4*)Wb)[k];
        float4 wd = ((const float4*)Wd)[k];
        float4 wm = ((const float4*)Wm)[k];
        acc[0] += h * wb.x; acc[1] += h * wb.y; acc[2] += h * wb.z; acc[3] += h * wb.w;
        acc[4] += h * wd.x; acc[5] += h * wd.y; acc[6] += h * wd.z; acc[7] += h * wd.w;
        acc[8] += h * wm.x; acc[9] += h * wm.y; acc[10] += h * wm.z; acc[11] += h * wm.w;
    }
#pragma unroll
    for (int j = 0; j < 12; j++)
        for (int off = 32; off; off >>= 1) acc[j] += __shfl_xor(acc[j], off, 64);
    if (lane < 4) {
        beta[(size_t)row * 4 + lane] = sigmoidf_(acc[lane]);
        gamma[(size_t)row * 4 + lane] = sigmoidf_(acc[4 + lane]);
        xmix[(size_t)row * 4 + lane] = acc[8 + lane];
    }
}

// ---------------- K5 (fused): conv + silu(+silu) + per-head l2norm -> qn/kn bf16; v -> bf16 ----------------
// TB consecutive timesteps per block (one b). Accumulate-on-arrival ring: each row read ONCE.
__global__ __launch_bounds__(256) void k_convnorm(const unsigned short* __restrict__ xqkv,
                                                  const float* __restrict__ cq,
                                                  const float* __restrict__ ck,
                                                  const float* __restrict__ cv,
                                                  unsigned short* __restrict__ qn,
                                                  unsigned short* __restrict__ kn,
                                                  unsigned short* __restrict__ vb)
{
    int blk = blockIdx.x;                 // B*(L/TB) blocks
    int b = blk >> 7;                     // L/TB = 128
    int t0 = (blk & 127) * TB;
    int tid = threadIdx.x;
    int h = tid >> 6, lane = tid & 63;
    int c = tid * 4;

    // conv weights [ch][tap], loaded once per block (L1/L2-resident)
    float wq[4][4], wk[4][4], wv[4][4];
#pragma unroll
    for (int j = 0; j < 4; j++) {
        float4 a = *(const float4*)(cq + (size_t)(c + j) * 4);
        wq[j][0] = a.x; wq[j][1] = a.y; wq[j][2] = a.z; wq[j][3] = a.w;
        float4 d4 = *(const float4*)(ck + (size_t)(c + j) * 4);
        wk[j][0] = d4.x; wk[j][1] = d4.y; wk[j][2] = d4.z; wk[j][3] = d4.w;
        float4 e = *(const float4*)(cv + (size_t)(c + j) * 4);
        wv[j][0] = e.x; wv[j][1] = e.y; wv[j][2] = e.z; wv[j][3] = e.w;
    }

    // accumulator ring [slot][ch]; slot of output t is (t - t0) & 3 (compile-time below)
    float aq[4][4], ak[4][4], av[4][4];
#pragma unroll
    for (int s = 0; s < 4; s++)
#pragma unroll
        for (int j = 0; j < 4; j++) { aq[s][j] = 0.f; ak[s][j] = 0.f; av[s][j] = 0.f; }

    const unsigned short* xb = xqkv + (size_t)(b * L) * (3 * D) + c;

    // prologue: rows t0-3..t0-1, contributions only to outputs >= t0
#pragma unroll
    for (int p = 0; p < 3; p++) {
        int r = t0 - 3 + p;
        if (r >= 0) {                     // block-uniform branch (only first block of each b skips)
            const unsigned short* pp = xb + (size_t)r * (3 * D);
            ushort4 xq = *(const ushort4*)pp;
            ushort4 xk = *(const ushort4*)(pp + D);
            ushort4 xv = *(const ushort4*)(pp + 2 * D);
            float fq[4] = {bf2f(xq.x), bf2f(xq.y), bf2f(xq.z), bf2f(xq.w)};
            float fk[4] = {bf2f(xk.x), bf2f(xk.y), bf2f(xk.z), bf2f(xk.w)};
            float fv[4] = {bf2f(xv.x), bf2f(xv.y), bf2f(xv.z), bf2f(xv.w)};
#pragma unroll
            for (int d = 3 - p; d <= 3; d++) {
                int s = (p + d + 1) & 3;  // ((r+d) - t0) & 3, compile-time
                int kk = 3 - d;           // out[t] += x[r] * w[kk], kk = r-t+3
#pragma unroll
                for (int j = 0; j < 4; j++) {
                    aq[s][j] += wq[j][kk] * fq[j];
                    ak[s][j] += wk[j][kk] * fk[j];
                    av[s][j] += wv[j][kk] * fv[j];
                }
            }
        }
    }

    // stage row t0
    ushort4 sq2[2], sk2[2], sv2[2];
    {
        const unsigned short* pp = xb + (size_t)t0 * (3 * D);
        sq2[0] = *(const ushort4*)pp;
        sk2[0] = *(const ushort4*)(pp + D);
        sv2[0] = *(const ushort4*)(pp + 2 * D);
    }

#pragma unroll
    for (int i = 0; i < TB; i++) {
        // prefetch row t0+i+1 (latency hidden under this iteration's finalize)
        if (i + 1 < TB) {
            const unsigned short* pp = xb + (size_t)(t0 + i + 1) * (3 * D);
            sq2[(i + 1) & 1] = *(const ushort4*)pp;
            sk2[(i + 1) & 1] = *(const ushort4*)(pp + D);
            sv2[(i + 1) & 1] = *(const ushort4*)(pp + 2 * D);
        }
        // accumulate row t0+i into pending outputs t0+i .. t0+i+3
        {
            ushort4 xq = sq2[i & 1], xk = sk2[i & 1], xv = sv2[i & 1];
            float fq[4] = {bf2f(xq.x), bf2f(xq.y), bf2f(xq.z), bf2f(xq.w)};
            float fk[4] = {bf2f(xk.x), bf2f(xk.y), bf2f(xk.z), bf2f(xk.w)};
            float fv[4] = {bf2f(xv.x), bf2f(xv.y), bf2f(xv.z), bf2f(xv.w)};
#pragma unroll
            for (int d = 0; d < 4; d++) {
                if (i + d < TB) {         // compile-time: skip contributions to outputs beyond block
                    int s = (i + d) & 3;
                    int kk = 3 - d;
#pragma unroll
                    for (int j = 0; j < 4; j++) {
                        aq[s][j] += wq[j][kk] * fq[j];
                        ak[s][j] += wk[j][kk] * fk[j];
                        av[s][j] += wv[j][kk] * fv[j];
                    }
                }
            }
        }
        // finalize output t = t0+i from slot i&3
        {
            const int s = i & 3;
            float rq[4], rk[4], rv[4];
#pragma unroll
            for (int j = 0; j < 4; j++) {
                rq[j] = siluf_(siluf_(aq[s][j]));
                rk[j] = siluf_(siluf_(ak[s][j]));
                rv[j] = siluf_(av[s][j]);
            }
            float sqs = rq[0] * rq[0] + rq[1] * rq[1] + rq[2] * rq[2] + rq[3] * rq[3];
            float sks = rk[0] * rk[0] + rk[1] * rk[1] + rk[2] * rk[2] + rk[3] * rk[3];
            for (int off = 32; off; off >>= 1) {
                sqs += __shfl_xor(sqs, off, 64);
                sks += __shfl_xor(sks, off, 64);
            }
            float qs = rsqrtf(sqs + 1e-6f), ks = rsqrtf(sks + 1e-6f);
            int t = t0 + i;
            size_t oidx = ((size_t)(b * NH + h) * L + t) * DK + lane * 4;
            ushort4 oq, ok, ov;
            oq.x = f2bf(rq[0] * qs); oq.y = f2bf(rq[1] * qs); oq.z = f2bf(rq[2] * qs); oq.w = f2bf(rq[3] * qs);
            ok.x = f2bf(rk[0] * ks); ok.y = f2bf(rk[1] * ks); ok.z = f2bf(rk[2] * ks); ok.w = f2bf(rk[3] * ks);
            ov.x = f2bf(rv[0]); ov.y = f2bf(rv[1]); ov.z = f2bf(rv[2]); ov.w = f2bf(rv[3]);
            *(ushort4*)(qn + oidx) = oq;
            *(ushort4*)(kn + oidx) = ok;
            *(ushort4*)(vb + (size_t)(b * L + t) * D + c) = ov;
            // reset slot for output t+4 (first contribution arrives next iteration)
            if (i + 4 < TB) {
#pragma unroll
                for (int j = 0; j < 4; j++) { aq[s][j] = 0.f; ak[s][j] = 0.f; av[s][j] = 0.f; }
            }
        }
    }
}

// ---------------- K6: mix conv + silu ----------------
__global__ __launch_bounds__(256) void k_convmix(const float* xmix, const float* cmix, float* mixinp)
{
    int idx = blockIdx.x * 256 + threadIdx.x;   // < B*L*NH
    int h = idx & 3;
    int t = (idx >> 2) & (L - 1);
    int b = idx >> 13;
    float acc = 0.f;
#pragma unroll
    for (int kk = 0; kk < 4; kk++) {
        int tt = t - 3 + kk;
        if (tt >= 0) acc += cmix[h * 4 + kk] * xmix[((size_t)(b * L + tt) << 2) + h];
    }
    mixinp[idx] = siluf_(acc);
}

// ---------------- K7b: per-(bh,chunk) delta-rule precompute (MFMA version) ----------------
#define KTS 40   // LDS row stride in shorts: 80B (16B-aligned), dword stride 20 -> 2-way banks (free)
__global__ __launch_bounds__(256) void k_delta_pre(const unsigned short* qn, const unsigned short* kn,
                                                   const unsigned short* vb, const float* beta,
                                                   unsigned short* wneg, unsigned short* knT,
                                                   unsigned short* attnb, float* u)
{
    __shared__ __align__(16) unsigned short kTl[256 * KTS]; // k^T bf16 [dk][t]
    __shared__ __align__(16) unsigned short vTl[256 * KTS]; // v^T bf16 [dk][t]
    __shared__ __align__(16) unsigned short T2b[32 * KTS];  // T2 bf16 [t][t']
    __shared__ float Gs[32 * 33];
    int bx = blockIdx.x;
    int bh = bx >> 6, ch = bx & 63;
    int b = bh >> 2, h = bh & 3;
    int t0 = ch * 32;
    int tid = threadIdx.x;
    int w = tid >> 6, lane = tid & 63;
    int r16 = lane & 15, quad = lane >> 4;
    size_t rowbase = (size_t)(bh * L + t0);
    f32x4 z4 = {0.f, 0.f, 0.f, 0.f};

    // ---- phase A: MFMA G/QK tiles
    if (w < 3) {
        int mi = (w == 0) ? 0 : 1;
        int ni = (w == 2) ? 1 : 0;
        const unsigned short* krm = kn + (rowbase + mi * 16 + r16) * DK;
        const unsigned short* krn = kn + (rowbase + ni * 16 + r16) * DK;
        const unsigned short* qrm = qn + (rowbase + mi * 16 + r16) * DK;
        f32x4 g = z4, qk = z4;
#pragma unroll
        for (int kt = 0; kt < 8; kt++) {
            bf16x8 a  = *(const bf16x8*)(krm + kt * 32 + quad * 8);
            bf16x8 bb = *(const bf16x8*)(krn + kt * 32 + quad * 8);
            bf16x8 qa = *(const bf16x8*)(qrm + kt * 32 + quad * 8);
            g  = MFMA16(a, bb, g);
            qk = MFMA16(qa, bb, qk);
        }
#pragma unroll
        for (int r = 0; r < 4; r++) {
            int i = mi * 16 + quad * 4 + r, j = ni * 16 + r16;
            Gs[i * 33 + j] = g[r];
            attnb[(size_t)(bh * 64 + ch) * 1024 + i * 32 + j] =
                (j <= i) ? f2bf(qk[r]) : (unsigned short)0;
        }
    } else {
        // strictly-upper QK tile (0,1) is all zero
#pragma unroll
        for (int r = 0; r < 4; r++) {
            int i = quad * 4 + r, j = 16 + r16;
            attnb[(size_t)(bh * 64 + ch) * 1024 + i * 32 + j] = 0;
        }
    }
    // ---- phase A2 (all threads): transpose k, v (both bf16) into LDS
    {
        int t = tid & 31, c0 = (tid >> 5) * 32;
        const unsigned short* krow = kn + (rowbase + t) * DK + c0;
        const unsigned short* vrow = vb + ((size_t)(b * L + t0 + t)) * D + h * DK + c0;
#pragma unroll
        for (int j = 0; j < 32; j += 4) {
            ushort4 kv = *(const ushort4*)(krow + j);
            ushort4 vv = *(const ushort4*)(vrow + j);
            kTl[(c0 + j + 0) * KTS + t] = kv.x;
            kTl[(c0 + j + 1) * KTS + t] = kv.y;
            kTl[(c0 + j + 2) * KTS + t] = kv.z;
            kTl[(c0 + j + 3) * KTS + t] = kv.w;
            vTl[(c0 + j + 0) * KTS + t] = vv.x;
            vTl[(c0 + j + 1) * KTS + t] = vv.y;
            vTl[(c0 + j + 2) * KTS + t] = vv.z;
            vTl[(c0 + j + 3) * KTS + t] = vv.w;
        }
    }
    __syncthreads();

    // ---- phase B
    if (w == 0) {
        int c = lane & 31;
        float rr[32];
#pragma unroll
        for (int j = 0; j < 32; j++) rr[j] = Gs[j * 33 + c];
        // Row 0 of the strict-lower T is empty: must be zero.
        rr[0] = 0.f;
        float bc = beta[(size_t)(b * L + t0 + c) * NH + h];
#pragma unroll
        for (int i = 1; i < 32; i++) {
            float bi = __shfl(bc, i, 64);
            float s = -bi * rr[i];
#pragma unroll
            for (int j = 1; j < i; j++) {
                float aij = -bi * __shfl(rr[i], j, 64);
                s += aij * ((c < j) ? rr[j] : 0.f);
            }
            rr[i] = (c < i) ? s : 0.f;
        }
        if (lane < 32) {
#pragma unroll
            for (int i = 0; i < 32; i++) {
                float val = (rr[i] + ((i == c) ? 1.f : 0.f)) * bc;
                T2b[i * KTS + c] = f2bf(val);
            }
        }
    } else {
        int idx = tid - 64;
        for (int rowc = idx; rowc < 256; rowc += 192) {
            unsigned short* kT = knT + ((size_t)(bh * 64 + ch) * DK + rowc) * 32;
#pragma unroll
            for (int seg = 0; seg < 4; seg++) {
                uint4 d = *(const uint4*)&kTl[rowc * KTS + seg * 8];
                *(uint4*)(kT + seg * 8) = d;
            }
        }
    }
    __syncthreads();

    // ---- phase C: u = T2@v (f32 out), wneg = -(T2@k) (bf16 out)
#pragma unroll
    for (int mt = 0; mt < 2; mt++) {
        bf16x8 ta = *(const bf16x8*)&T2b[(mt * 16 + r16) * KTS + quad * 8];
#pragma unroll
        for (int nt2 = 0; nt2 < 4; nt2++) {
            int nt = w * 4 + nt2;
            bf16x8 vb2 = *(const bf16x8*)&vTl[(nt * 16 + r16) * KTS + quad * 8];
            bf16x8 kb = *(const bf16x8*)&kTl[(nt * 16 + r16) * KTS + quad * 8];
            f32x4 uu = MFMA16(ta, vb2, z4);
            f32x4 ww = MFMA16(ta, kb, z4);
            float* ug = u + (rowbase + mt * 16 + quad * 4) * DK + nt * 16 + r16;
            unsigned short* wg = wneg + (rowbase + mt * 16 + quad * 4) * DK + nt * 16 + r16;
#pragma unroll
            for (int r = 0; r < 4; r++) {
                ug[(size_t)r * DK] = uu[r];
                wg[(size_t)r * DK] = f2bf(-ww[r]);
            }
        }
    }
}

// ---------------- K8a: EMA local scan (bf16 v input) ----------------
__global__ __launch_bounds__(256) void k_ema_local(const unsigned short* v, const float* gamma,
                                                   float* ema_local, float* Acum,
                                                   float* s_end, float* Pchunk)
{
    __shared__ float gsh[ET];
    int blk = blockIdx.x;
    int bh = blk >> 5;
    int ch = blk & (ENCH - 1);
    int b = bh >> 2, h = bh & 3;
    int c = threadIdx.x;
    int t0 = ch * ET;
    if (c < ET) gsh[c] = gamma[(size_t)(b * L + t0 + c) * NH + h];
    __syncthreads();
    const unsigned short* vg = v + (size_t)(b * L + t0) * D + h * DK + c;
    float* eg = ema_local + (size_t)(b * L + t0) * D + h * DK + c;
    float* Ag = Acum + (size_t)bh * L + t0;
    float s = 0.f;
    float A = 1.f;
#pragma unroll 8
    for (int i = 0; i < ET; i++) {
        float g = gsh[i];
        s = g * s + (1.f - g) * bf2f(vg[(size_t)i * D]);
        A *= g;
        eg[(size_t)i * D] = s;
        if (c == 0) Ag[i] = A;
    }
    s_end[((size_t)bh * ENCH + ch) * DK + c] = s;
    if (c == 0) Pchunk[(size_t)bh * ENCH + ch] = A;
}

// ---------------- K8b: EMA carry scan ----------------
__global__ __launch_bounds__(256) void k_ema_carry(const float* s_end, const float* Pchunk, float* S_in)
{
    int bh = blockIdx.x;
    int c = threadIdx.x;
    float S = 0.f;
    for (int ch = 0; ch < ENCH; ch++) {
        S_in[((size_t)bh * ENCH + ch) * DK + c] = S;
        float P = Pchunk[(size_t)bh * ENCH + ch];
        S = P * S + s_end[((size_t)bh * ENCH + ch) * DK + c];
    }
}

// ---------------- K9: sequential inter-chunk scan (R1 version — best measured: 90us) ----------------
#define STS 280   // st row stride in shorts (dword stride 140 = 12 mod 32 -> 2-way)
#define USTR 40   // uat row stride in shorts (2-way only)
__global__ __launch_bounds__(128, 1) void k_scan(const unsigned short* qn, const unsigned short* wneg,
                                                 const unsigned short* knT, const unsigned short* attnb,
                                                 const float* u, float* od)
{
    __shared__ __align__(16) unsigned short st[16 * STS];   // S^T bf16: [c][dk]
    __shared__ __align__(16) unsigned short uat[16 * USTR]; // u_adj^T bf16: [c][t]
    int bh = blockIdx.x;
    int tile = blockIdx.y;      // 0..15, 16 cols each
    int b = bh >> 2, h = bh & 3;
    int mo = threadIdx.x >> 6, lane = threadIdx.x & 63;
    int r16 = lane & 15, quad = lane >> 4;
    int cbase = tile * 16;
    f32x4 z4 = {0.f, 0.f, 0.f, 0.f};
    f32x4 sacc[8];
#pragma unroll
    for (int a = 0; a < 8; a++) sacc[a] = z4;
    const unsigned short* qb = qn + (size_t)bh * L * DK;
    const unsigned short* wb = wneg + (size_t)bh * L * DK;
    const float* ub = u + (size_t)bh * L * DK;
    const unsigned short* kTbase = knT + (size_t)bh * 64 * DK * 32;
    const unsigned short* atbase = attnb + (size_t)bh * 64 * 1024;
    int dkb = mo * 128;   // this wave's S^T row base

    bf16x8 qf[2][8], wf[2][8];
    f32x4 au0[2];

    auto issue = [&](int ch, int par) {
        int t0 = ch * 32;
        const unsigned short* wrow = wb + (size_t)(t0 + 16 * mo + r16) * DK;
        const unsigned short* qrow = qb + (size_t)(t0 + 16 * mo + r16) * DK;
#pragma unroll
        for (int kt = 0; kt < 8; kt++) {
            qf[par][kt] = *(const bf16x8*)(qrow + kt * 32 + quad * 8);
            wf[par][kt] = *(const bf16x8*)(wrow + kt * 32 + quad * 8);
        }
        const float* up = ub + (size_t)(t0 + 16 * mo + quad * 4) * DK + cbase + r16;
        f32x4 a; a[0] = up[0]; a[1] = up[DK]; a[2] = up[2 * DK]; a[3] = up[3 * DK];
        au0[par] = a;
    };

    issue(0, 0);

    auto body = [&](int ch, int par) {
        int t0 = ch * 32;
        // (0) issue current-chunk kf/af early — consumed only at (F)
        bf16x8 af = *(const bf16x8*)(atbase + (size_t)ch * 1024 + (16 * mo + r16) * 32 + quad * 8);
        const unsigned short* kTb = kTbase + (size_t)ch * DK * 32;
        bf16x8 kf[8];
#pragma unroll
        for (int a = 0; a < 8; a++)
            kf[a] = *(const bf16x8*)(kTb + (size_t)(dkb + a * 16 + r16) * 32 + quad * 8);

        // (A) write this wave's S^T slab to LDS
#pragma unroll
        for (int a = 0; a < 8; a++) {
            uint2 p;
            p.x = f2bf(sacc[a][0]) | ((unsigned)f2bf(sacc[a][1]) << 16);
            p.y = f2bf(sacc[a][2]) | ((unsigned)f2bf(sacc[a][3]) << 16);
            *(uint2*)&st[r16 * STS + dkb + a * 16 + quad * 4] = p;
        }
        // (B) prefetch next chunk's qf/wf/au0
        if (ch + 1 < NCH) issue(ch + 1, par ^ 1);
        bar_lds();

        // (C) u_adj = u - w@S ; o_partial = q@S
        f32x4 au = au0[par], ao = z4;
#pragma unroll
        for (int kt = 0; kt < 8; kt++) {
            bf16x8 sfr = *(const bf16x8*)&st[r16 * STS + kt * 32 + quad * 8];
            au = MFMA16(wf[par][kt], sfr, au);
            ao = MFMA16(qf[par][kt], sfr, ao);
        }
        // (D) write u_adj^T
        {
            uint2 p;
            p.x = f2bf(au[0]) | ((unsigned)f2bf(au[1]) << 16);
            p.y = f2bf(au[2]) | ((unsigned)f2bf(au[3]) << 16);
            *(uint2*)&uat[r16 * USTR + 16 * mo + quad * 4] = p;
        }
        bar_lds();

        // (F) o = q@S + attn@u_adj ; store ; S^T += kT @ u_adj
        {
            bf16x8 uf = *(const bf16x8*)&uat[r16 * USTR + quad * 8];
            ao = MFMA16(af, uf, ao);
            float* op = od + (size_t)(b * L + t0 + 16 * mo + quad * 4) * D + h * DK + cbase + r16;
            op[0] = ao[0]; op[D] = ao[1]; op[2 * D] = ao[2]; op[3 * D] = ao[3];
#pragma unroll
            for (int a = 0; a < 8; a++)
                sacc[a] = MFMA16(kf[a], uf, sacc[a]);
        }
    };

    for (int ch2 = 0; ch2 < NCH; ch2 += 2) {
        body(ch2, 0);
        body(ch2 + 1, 1);
    }
}

// ---------------- K10: mix + EMA fix-up + per-head RMS norm -> bf16 ----------------
__global__ __launch_bounds__(256) void k_mixrms(const float* od, const float* ema_local,
                                                const float* Acum, const float* S_in,
                                                const float* mixinp,
                                                const float* mix_bias, const float* rms_w,
                                                unsigned short* onorm)
{
    int row = blockIdx.x;       // b*L + t
    int tid = threadIdx.x;
    int h = tid >> 6, lane = tid & 63;
    int b = row >> 11, t = row & (L - 1);
    int bh = b * NH + h;
    int ch = t >> 6;            // ET = 64
    float m = sigmoidf_(mixinp[(size_t)row * NH + h] + mix_bias[h]);
    int c = tid * 4;
    float A = Acum[(size_t)bh * L + t];
    float4 sin4 = *(const float4*)(S_in + ((size_t)bh * ENCH + ch) * DK + (c & (DK - 1)));
    float4 o = *(const float4*)(od + (size_t)row * D + c);
    float4 e = *(const float4*)(ema_local + (size_t)row * D + c);
    e.x += A * sin4.x; e.y += A * sin4.y; e.z += A * sin4.z; e.w += A * sin4.w;
    float x0 = o.x + m * (e.x - o.x);
    float x1 = o.y + m * (e.y - o.y);
    float x2 = o.z + m * (e.z - o.z);
    float x3 = o.w + m * (e.w - o.w);
    float ss = x0 * x0 + x1 * x1 + x2 * x2 + x3 * x3;
    for (int off = 32; off; off >>= 1) ss += __shfl_xor(ss, off, 64);
    float scale = rsqrtf(ss * (1.0f / 256.0f) + 1e-5f);
    float4 w = *(const float4*)(rms_w + lane * 4);
    uint2 p;
    p.x = f2bf(x0 * scale * w.x) | ((unsigned)f2bf(x1 * scale * w.y) << 16);
    p.y = f2bf(x2 * scale * w.z) | ((unsigned)f2bf(x3 * scale * w.w) << 16);
    *(uint2*)(onorm + (size_t)row * D + c) = p;
}

extern "C" void kernel_launch(void* const* d_in, const int* in_sizes, int n_in,
                              void* d_out, int out_size, void* d_ws, size_t ws_size,
                              hipStream_t stream)
{
    (void)in_sizes; (void)n_in; (void)out_size; (void)ws_size;
    const float* hidden   = (const float*)d_in[0];
    const float* Wq       = (const float*)d_in[1];
    const float* Wk       = (const float*)d_in[2];
    const float* Wv       = (const float*)d_in[3];
    const float* conv_q   = (const float*)d_in[4];
    const float* conv_k   = (const float*)d_in[5];
    const float* conv_v   = (const float*)d_in[6];
    const float* Wb       = (const float*)d_in[7];
    const float* Wdec     = (const float*)d_in[8];
    const float* Wmix     = (const float*)d_in[9];
    const float* conv_mix = (const float*)d_in[10];
    const float* mix_bias = (const float*)d_in[11];
    const float* rms_w    = (const float*)d_in[12];
    const float* Wo       = (const float*)d_in[13];
    float* out = (float*)d_out;

    char* ws = (char*)d_ws;
    size_t off = 0;
    auto alloc = [&](size_t bytes) -> char* {
        char* p = ws + off;
        off += (bytes + 255) & ~(size_t)255;
        return p;
    };
    unsigned short* wT    = (unsigned short*)alloc((size_t)4 * D * D * 2);
    unsigned short* hidB  = (unsigned short*)alloc((size_t)B * L * D * 2);
    unsigned short* xqkv  = (unsigned short*)alloc((size_t)B * L * 3 * D * 2); // slices 1,2 reused as wneg/knT
    float* beta   = (float*)alloc((size_t)B * L * NH * 4);
    float* gamma  = (float*)alloc((size_t)B * L * NH * 4);
    float* xmix   = (float*)alloc((size_t)B * L * NH * 4);
    float* mixinp = (float*)alloc((size_t)B * L * NH * 4);
    float* qbuf   = (float*)alloc((size_t)B * L * D * 4);   // ema_local
    float* kbuf   = (float*)alloc((size_t)B * L * D * 4);   // od
    unsigned short* vb = (unsigned short*)alloc((size_t)B * L * D * 2);  // v bf16
    float* u      = (float*)alloc((size_t)B * L * D * 4);
    unsigned short* attnb = (unsigned short*)alloc((size_t)BH * NCH * CHUNK * CHUNK * 2);
    unsigned short* onorm = (unsigned short*)alloc((size_t)B * L * D * 2);
    unsigned short* kn    = (unsigned short*)alloc((size_t)B * L * D * 2);
    unsigned short* qn    = (unsigned short*)alloc((size_t)B * L * D * 2);
    float* Acum   = (float*)alloc((size_t)BH * L * 4);
    float* s_end  = (float*)alloc((size_t)BH * ENCH * DK * 4);
    float* Pchunk = (float*)alloc((size_t)BH * ENCH * 4);
    float* S_in   = (float*)alloc((size_t)BH * ENCH * DK * 4);

    unsigned short* wneg = xqkv + (size_t)B * L * D;       // xqkv dead after k_convnorm
    unsigned short* knT  = xqkv + (size_t)2 * B * L * D;
    float* ema_local = qbuf;
    float* od  = kbuf;

    k_wT<<<dim3(32, 32, 4), 256, 0, stream>>>(Wq, Wk, Wv, Wo, wT);
    k_cvt<<<dim3(2048), 256, 0, stream>>>(hidden, hidB, B * L * D / 4);
    k_gemm_lds<3 * D, false><<<dim3(64, 24), 256, 0, stream>>>(hidB, wT, xqkv);
    k_smallproj<<<dim3(B * L / 4), 256, 0, stream>>>(hidden, Wb, Wdec, Wmix, beta, gamma, xmix);
    k_convnorm<<<dim3(B * L / TB), 256, 0, stream>>>(xqkv, conv_q, conv_k, conv_v, qn, kn, vb);
    k_convmix<<<dim3(B * L * NH / 256), 256, 0, stream>>>(xmix, conv_mix, mixinp);
    k_delta_pre<<<dim3(BH * NCH), 256, 0, stream>>>(qn, kn, vb, beta, wneg, knT, attnb, u);
    k_ema_local<<<dim3(BH * ENCH), 256, 0, stream>>>(vb, gamma, ema_local, Acum, s_end, Pchunk);
    k_ema_carry<<<dim3(BH), 256, 0, stream>>>(s_end, Pchunk, S_in);
    k_scan<<<dim3(16, 16), 128, 0, stream>>>(qn, wneg, knT, attnb, u, od);
    k_mixrms<<<dim3(B * L), 256, 0, stream>>>(od, ema_local, Acum, S_in, mixinp, mix_bias, rms_w, onorm);
    k_gemm_lds<D, true><<<dim3(64, 8), 256, 0, stream>>>(onorm, wT + (size_t)3 * D * D, out);
}

// Round 8
// 451.256 us; speedup vs baseline: 1.1713x; 1.0183x over previous
//
#include <hip/hip_runtime.h>
#include <hip/hip_bf16.h>

#define B 4
#define L 2048
#define D 1024
#define NH 4
#define DK 256
#define CHUNK 32
#define NCH 64
#define BH (B*NH)
// EMA chunking
#define ET 64
#define ENCH (L/ET)
// conv kernel: timesteps per block
#define TB 16

typedef __attribute__((ext_vector_type(8))) __bf16 bf16x8;
typedef __attribute__((ext_vector_type(4))) __bf16 bf16x4;
typedef __attribute__((ext_vector_type(4))) float f32x4;

__device__ inline unsigned short f2bf(float f) {
    union { float f; unsigned u; } v; v.f = f;
    unsigned r = v.u + 0x7fffu + ((v.u >> 16) & 1u);
    return (unsigned short)(r >> 16);
}
__device__ inline float bf2f(unsigned short h) {
    union { unsigned u; float f; } v; v.u = ((unsigned)h) << 16; return v.f;
}
__device__ inline float sigmoidf_(float x) { return 1.0f / (1.0f + __expf(-x)); }
__device__ inline float siluf_(float x) { return x / (1.0f + __expf(-x)); }

#define MFMA16(a, b, c) __builtin_amdgcn_mfma_f32_16x16x32_bf16((a), (b), (c), 0, 0, 0)

// raw barrier: wait only LDS (lgkmcnt(0)), leave global loads in flight.
// 0xC07F = vmcnt(63) expcnt(7) lgkmcnt(0)
__device__ inline void bar_lds() {
    __builtin_amdgcn_s_waitcnt(0xC07F);
    __builtin_amdgcn_s_barrier();
}

// async global->LDS, 16B per lane; lds dest = wave-uniform base + lane*16
__device__ inline void load_lds16(const unsigned short* g, unsigned short* l) {
    __builtin_amdgcn_global_load_lds(
        (const __attribute__((address_space(1))) unsigned int*)g,
        (__attribute__((address_space(3))) unsigned int*)l, 16, 0, 0);
}

// ---------------- K1: transpose+convert weights: W (K,N) f32 -> WT (N,K) bf16 ----------------
__global__ __launch_bounds__(256) void k_wT(const float* Wq, const float* Wk, const float* Wv,
                                            const float* Wo, unsigned short* wT)
{
    __shared__ float tile[32][33];
    int z = blockIdx.z;
    const float* W = (z == 0) ? Wq : (z == 1) ? Wk : (z == 2) ? Wv : Wo;
    unsigned short* out = wT + (size_t)z * D * D;
    int kt = blockIdx.x * 32, nt = blockIdx.y * 32;
    int tx = threadIdx.x & 31, ty = threadIdx.x >> 5;
#pragma unroll
    for (int i = 0; i < 4; i++)
        tile[ty + 8 * i][tx] = W[(size_t)(kt + ty + 8 * i) * D + nt + tx];
    __syncthreads();
#pragma unroll
    for (int i = 0; i < 4; i++)
        out[(size_t)(nt + ty + 8 * i) * D + kt + tx] = f2bf(tile[tx][ty + 8 * i]);
}

// ---------------- K3: LDS-staged 128x128 GEMM (m97 structure) + XCD-local block remap ----------------
// XCD k (= linear_block_id & 7, assuming round-robin dispatch) owns M-tiles [k*8,(k+1)*8)
// across all N-tiles -> its A-panel (8*128 rows x 1024 K x 2B = 2MB) stays L2-resident
// instead of being re-fetched from L3 once per N-tile. Bijective for gridDim.x==64.
// If the dispatch->XCD mapping assumption is wrong this is just a permutation (perf-neutral).
template<int NTOT, bool OUT_F32>
__global__ __launch_bounds__(256) void k_gemm_lds(const unsigned short* __restrict__ A,
                                                  const unsigned short* __restrict__ BT,
                                                  void* __restrict__ outp)
{
    __shared__ __align__(16) unsigned short As[128 * 32];   // 8 KB
    __shared__ __align__(16) unsigned short Bs[128 * 32];   // 8 KB
    const int K = 1024;
    int tid = threadIdx.x;
    int w = tid >> 6, lane = tid & 63;
    int r16 = lane & 15, quad = lane >> 4;
    int wm = w & 1, wn = w >> 1;
    int lin = blockIdx.x + gridDim.x * blockIdx.y;
    int xcd = lin & 7, tt = lin >> 3;
    int bm = (xcd * 8 + (tt & 7)) * 128;
    int bn = (tt >> 3) * 128;
    int lrow = lane >> 2;            // 0..15
    int lcol = (lane & 3) * 8;       // element col within 32
    f32x4 z4 = {0.f, 0.f, 0.f, 0.f};
    f32x4 acc[4][4];
#pragma unroll
    for (int i = 0; i < 4; i++)
#pragma unroll
        for (int j = 0; j < 4; j++) acc[i][j] = z4;

    for (int kt = 0; kt < K; kt += 32) {
#pragma unroll
        for (int j = 0; j < 2; j++) {
            int r0 = (w * 2 + j) * 16;
            load_lds16(A + (size_t)(bm + r0 + lrow) * K + kt + lcol, &As[r0 * 32]);
            load_lds16(BT + (size_t)(bn + r0 + lrow) * K + kt + lcol, &Bs[r0 * 32]);
        }
        __syncthreads();
        bf16x8 af[4], bf[4];
#pragma unroll
        for (int ms = 0; ms < 4; ms++)
            af[ms] = *(const bf16x8*)&As[(wm * 64 + ms * 16 + r16) * 32 + quad * 8];
#pragma unroll
        for (int ns = 0; ns < 4; ns++)
            bf[ns] = *(const bf16x8*)&Bs[(wn * 64 + ns * 16 + r16) * 32 + quad * 8];
#pragma unroll
        for (int ms = 0; ms < 4; ms++)
#pragma unroll
            for (int ns = 0; ns < 4; ns++)
                acc[ms][ns] = MFMA16(af[ms], bf[ns], acc[ms][ns]);
        __syncthreads();
    }
#pragma unroll
    for (int ms = 0; ms < 4; ms++)
#pragma unroll
        for (int ns = 0; ns < 4; ns++)
#pragma unroll
            for (int r = 0; r < 4; r++) {
                int m = bm + wm * 64 + ms * 16 + quad * 4 + r;
                int n = bn + wn * 64 + ns * 16 + r16;
                if (OUT_F32)
                    ((float*)outp)[(size_t)m * NTOT + n] = acc[ms][ns][r];
                else
                    ((unsigned short*)outp)[(size_t)m * NTOT + n] = f2bf(acc[ms][ns][r]);
            }
}

// ---------------- K4 (fused): small projections + hidden f32->bf16 convert ----------------
// hidden read ONCE (was read twice by k_cvt + k_smallproj); k_cvt launch removed.
__global__ __launch_bounds__(256) void k_smallproj(const float* hid, const float* Wb, const float* Wd,
                                                   const float* Wm, float* beta, float* gamma, float* xmix,
                                                   unsigned short* hb)
{
    int wave = threadIdx.x >> 6, lane = threadIdx.x & 63;
    int row = blockIdx.x * 4 + wave;
    const float* hrow = hid + (size_t)row * D;
    unsigned short* hbrow = hb + (size_t)row * D;
    float acc[12];
#pragma unroll
    for (int j = 0; j < 12; j++) acc[j] = 0.f;
    for (int i = 0; i < 16; i++) {
        int k = lane + 64 * i;
        float h = hrow[k];
        hbrow[k] = f2bf(h);
        float4 wb = ((const float4*)Wb)[k];
        float4 wd = ((const float4*)Wd)[k];
        float4 wm = ((const float4*)Wm)[k];
        acc[0] += h * wb.x; acc[1] += h * wb.y; acc[2] += h * wb.z; acc[3] += h * wb.w;
        acc[4] += h * wd.x; acc[5] += h * wd.y; acc[6] += h * wd.z; acc[7] += h * wd.w;
        acc[8] += h * wm.x; acc[9] += h * wm.y; acc[10] += h * wm.z; acc[11] += h * wm.w;
    }
#pragma unroll
    for (int j = 0; j < 12; j++)
        for (int off = 32; off; off >>= 1) acc[j] += __shfl_xor(acc[j], off, 64);
    if (lane < 4) {
        beta[(size_t)row * 4 + lane] = sigmoidf_(acc[lane]);
        gamma[(size_t)row * 4 + lane] = sigmoidf_(acc[4 + lane]);
        xmix[(size_t)row * 4 + lane] = acc[8 + lane];
    }
}

// ---------------- K5 (fused): conv + silu(+silu) + per-head l2norm -> qn/kn bf16; v -> bf16 ----------------
// TB consecutive timesteps per block (one b). Accumulate-on-arrival ring: each row read ONCE.
__global__ __launch_bounds__(256) void k_convnorm(const unsigned short* __restrict__ xqkv,
                                                  const float* __restrict__ cq,
                                                  const float* __restrict__ ck,
                                                  const float* __restrict__ cv,
                                                  unsigned short* __restrict__ qn,
                                                  unsigned short* __restrict__ kn,
                                                  unsigned short* __restrict__ vb)
{
    int blk = blockIdx.x;                 // B*(L/TB) blocks
    int b = blk >> 7;                     // L/TB = 128
    int t0 = (blk & 127) * TB;
    int tid = threadIdx.x;
    int h = tid >> 6, lane = tid & 63;
    int c = tid * 4;

    // conv weights [ch][tap], loaded once per block (L1/L2-resident)
    float wq[4][4], wk[4][4], wv[4][4];
#pragma unroll
    for (int j = 0; j < 4; j++) {
        float4 a = *(const float4*)(cq + (size_t)(c + j) * 4);
        wq[j][0] = a.x; wq[j][1] = a.y; wq[j][2] = a.z; wq[j][3] = a.w;
        float4 d4 = *(const float4*)(ck + (size_t)(c + j) * 4);
        wk[j][0] = d4.x; wk[j][1] = d4.y; wk[j][2] = d4.z; wk[j][3] = d4.w;
        float4 e = *(const float4*)(cv + (size_t)(c + j) * 4);
        wv[j][0] = e.x; wv[j][1] = e.y; wv[j][2] = e.z; wv[j][3] = e.w;
    }

    // accumulator ring [slot][ch]; slot of output t is (t - t0) & 3 (compile-time below)
    float aq[4][4], ak[4][4], av[4][4];
#pragma unroll
    for (int s = 0; s < 4; s++)
#pragma unroll
        for (int j = 0; j < 4; j++) { aq[s][j] = 0.f; ak[s][j] = 0.f; av[s][j] = 0.f; }

    const unsigned short* xb = xqkv + (size_t)(b * L) * (3 * D) + c;

    // prologue: rows t0-3..t0-1, contributions only to outputs >= t0
#pragma unroll
    for (int p = 0; p < 3; p++) {
        int r = t0 - 3 + p;
        if (r >= 0) {                     // block-uniform branch (only first block of each b skips)
            const unsigned short* pp = xb + (size_t)r * (3 * D);
            ushort4 xq = *(const ushort4*)pp;
            ushort4 xk = *(const ushort4*)(pp + D);
            ushort4 xv = *(const ushort4*)(pp + 2 * D);
            float fq[4] = {bf2f(xq.x), bf2f(xq.y), bf2f(xq.z), bf2f(xq.w)};
            float fk[4] = {bf2f(xk.x), bf2f(xk.y), bf2f(xk.z), bf2f(xk.w)};
            float fv[4] = {bf2f(xv.x), bf2f(xv.y), bf2f(xv.z), bf2f(xv.w)};
#pragma unroll
            for (int d = 3 - p; d <= 3; d++) {
                int s = (p + d + 1) & 3;  // ((r+d) - t0) & 3, compile-time
                int kk = 3 - d;           // out[t] += x[r] * w[kk], kk = r-t+3
#pragma unroll
                for (int j = 0; j < 4; j++) {
                    aq[s][j] += wq[j][kk] * fq[j];
                    ak[s][j] += wk[j][kk] * fk[j];
                    av[s][j] += wv[j][kk] * fv[j];
                }
            }
        }
    }

    // stage row t0
    ushort4 sq2[2], sk2[2], sv2[2];
    {
        const unsigned short* pp = xb + (size_t)t0 * (3 * D);
        sq2[0] = *(const ushort4*)pp;
        sk2[0] = *(const ushort4*)(pp + D);
        sv2[0] = *(const ushort4*)(pp + 2 * D);
    }

#pragma unroll
    for (int i = 0; i < TB; i++) {
        // prefetch row t0+i+1 (latency hidden under this iteration's finalize)
        if (i + 1 < TB) {
            const unsigned short* pp = xb + (size_t)(t0 + i + 1) * (3 * D);
            sq2[(i + 1) & 1] = *(const ushort4*)pp;
            sk2[(i + 1) & 1] = *(const ushort4*)(pp + D);
            sv2[(i + 1) & 1] = *(const ushort4*)(pp + 2 * D);
        }
        // accumulate row t0+i into pending outputs t0+i .. t0+i+3
        {
            ushort4 xq = sq2[i & 1], xk = sk2[i & 1], xv = sv2[i & 1];
            float fq[4] = {bf2f(xq.x), bf2f(xq.y), bf2f(xq.z), bf2f(xq.w)};
            float fk[4] = {bf2f(xk.x), bf2f(xk.y), bf2f(xk.z), bf2f(xk.w)};
            float fv[4] = {bf2f(xv.x), bf2f(xv.y), bf2f(xv.z), bf2f(xv.w)};
#pragma unroll
            for (int d = 0; d < 4; d++) {
                if (i + d < TB) {         // compile-time: skip contributions to outputs beyond block
                    int s = (i + d) & 3;
                    int kk = 3 - d;
#pragma unroll
                    for (int j = 0; j < 4; j++) {
                        aq[s][j] += wq[j][kk] * fq[j];
                        ak[s][j] += wk[j][kk] * fk[j];
                        av[s][j] += wv[j][kk] * fv[j];
                    }
                }
            }
        }
        // finalize output t = t0+i from slot i&3
        {
            const int s = i & 3;
            float rq[4], rk[4], rv[4];
#pragma unroll
            for (int j = 0; j < 4; j++) {
                rq[j] = siluf_(siluf_(aq[s][j]));
                rk[j] = siluf_(siluf_(ak[s][j]));
                rv[j] = siluf_(av[s][j]);
            }
            float sqs = rq[0] * rq[0] + rq[1] * rq[1] + rq[2] * rq[2] + rq[3] * rq[3];
            float sks = rk[0] * rk[0] + rk[1] * rk[1] + rk[2] * rk[2] + rk[3] * rk[3];
            for (int off = 32; off; off >>= 1) {
                sqs += __shfl_xor(sqs, off, 64);
                sks += __shfl_xor(sks, off, 64);
            }
            float qs = rsqrtf(sqs + 1e-6f), ks = rsqrtf(sks + 1e-6f);
            int t = t0 + i;
            size_t oidx = ((size_t)(b * NH + h) * L + t) * DK + lane * 4;
            ushort4 oq, ok, ov;
            oq.x = f2bf(rq[0] * qs); oq.y = f2bf(rq[1] * qs); oq.z = f2bf(rq[2] * qs); oq.w = f2bf(rq[3] * qs);
            ok.x = f2bf(rk[0] * ks); ok.y = f2bf(rk[1] * ks); ok.z = f2bf(rk[2] * ks); ok.w = f2bf(rk[3] * ks);
            ov.x = f2bf(rv[0]); ov.y = f2bf(rv[1]); ov.z = f2bf(rv[2]); ov.w = f2bf(rv[3]);
            *(ushort4*)(qn + oidx) = oq;
            *(ushort4*)(kn + oidx) = ok;
            *(ushort4*)(vb + (size_t)(b * L + t) * D + c) = ov;
            // reset slot for output t+4 (first contribution arrives next iteration)
            if (i + 4 < TB) {
#pragma unroll
                for (int j = 0; j < 4; j++) { aq[s][j] = 0.f; ak[s][j] = 0.f; av[s][j] = 0.f; }
            }
        }
    }
}

// ---------------- K6: mix conv + silu ----------------
__global__ __launch_bounds__(256) void k_convmix(const float* xmix, const float* cmix, float* mixinp)
{
    int idx = blockIdx.x * 256 + threadIdx.x;   // < B*L*NH
    int h = idx & 3;
    int t = (idx >> 2) & (L - 1);
    int b = idx >> 13;
    float acc = 0.f;
#pragma unroll
    for (int kk = 0; kk < 4; kk++) {
        int tt = t - 3 + kk;
        if (tt >= 0) acc += cmix[h * 4 + kk] * xmix[((size_t)(b * L + tt) << 2) + h];
    }
    mixinp[idx] = siluf_(acc);
}

// ---------------- K7b: per-(bh,chunk) delta-rule precompute (MFMA version) ----------------
#define KTS 40   // LDS row stride in shorts: 80B (16B-aligned), dword stride 20 -> 2-way banks (free)
__global__ __launch_bounds__(256) void k_delta_pre(const unsigned short* qn, const unsigned short* kn,
                                                   const unsigned short* vb, const float* beta,
                                                   unsigned short* wneg, unsigned short* knT,
                                                   unsigned short* attnb, float* u)
{
    __shared__ __align__(16) unsigned short kTl[256 * KTS]; // k^T bf16 [dk][t]
    __shared__ __align__(16) unsigned short vTl[256 * KTS]; // v^T bf16 [dk][t]
    __shared__ __align__(16) unsigned short T2b[32 * KTS];  // T2 bf16 [t][t']
    __shared__ float Gs[32 * 33];
    int bx = blockIdx.x;
    int bh = bx >> 6, ch = bx & 63;
    int b = bh >> 2, h = bh & 3;
    int t0 = ch * 32;
    int tid = threadIdx.x;
    int w = tid >> 6, lane = tid & 63;
    int r16 = lane & 15, quad = lane >> 4;
    size_t rowbase = (size_t)(bh * L + t0);
    f32x4 z4 = {0.f, 0.f, 0.f, 0.f};

    // ---- phase A: MFMA G/QK tiles
    if (w < 3) {
        int mi = (w == 0) ? 0 : 1;
        int ni = (w == 2) ? 1 : 0;
        const unsigned short* krm = kn + (rowbase + mi * 16 + r16) * DK;
        const unsigned short* krn = kn + (rowbase + ni * 16 + r16) * DK;
        const unsigned short* qrm = qn + (rowbase + mi * 16 + r16) * DK;
        f32x4 g = z4, qk = z4;
#pragma unroll
        for (int kt = 0; kt < 8; kt++) {
            bf16x8 a  = *(const bf16x8*)(krm + kt * 32 + quad * 8);
            bf16x8 bb = *(const bf16x8*)(krn + kt * 32 + quad * 8);
            bf16x8 qa = *(const bf16x8*)(qrm + kt * 32 + quad * 8);
            g  = MFMA16(a, bb, g);
            qk = MFMA16(qa, bb, qk);
        }
#pragma unroll
        for (int r = 0; r < 4; r++) {
            int i = mi * 16 + quad * 4 + r, j = ni * 16 + r16;
            Gs[i * 33 + j] = g[r];
            attnb[(size_t)(bh * 64 + ch) * 1024 + i * 32 + j] =
                (j <= i) ? f2bf(qk[r]) : (unsigned short)0;
        }
    } else {
        // strictly-upper QK tile (0,1) is all zero
#pragma unroll
        for (int r = 0; r < 4; r++) {
            int i = quad * 4 + r, j = 16 + r16;
            attnb[(size_t)(bh * 64 + ch) * 1024 + i * 32 + j] = 0;
        }
    }
    // ---- phase A2 (all threads): transpose k, v (both bf16) into LDS
    {
        int t = tid & 31, c0 = (tid >> 5) * 32;
        const unsigned short* krow = kn + (rowbase + t) * DK + c0;
        const unsigned short* vrow = vb + ((size_t)(b * L + t0 + t)) * D + h * DK + c0;
#pragma unroll
        for (int j = 0; j < 32; j += 4) {
            ushort4 kv = *(const ushort4*)(krow + j);
            ushort4 vv = *(const ushort4*)(vrow + j);
            kTl[(c0 + j + 0) * KTS + t] = kv.x;
            kTl[(c0 + j + 1) * KTS + t] = kv.y;
            kTl[(c0 + j + 2) * KTS + t] = kv.z;
            kTl[(c0 + j + 3) * KTS + t] = kv.w;
            vTl[(c0 + j + 0) * KTS + t] = vv.x;
            vTl[(c0 + j + 1) * KTS + t] = vv.y;
            vTl[(c0 + j + 2) * KTS + t] = vv.z;
            vTl[(c0 + j + 3) * KTS + t] = vv.w;
        }
    }
    __syncthreads();

    // ---- phase B
    if (w == 0) {
        int c = lane & 31;
        float rr[32];
#pragma unroll
        for (int j = 0; j < 32; j++) rr[j] = Gs[j * 33 + c];
        // Row 0 of the strict-lower T is empty: must be zero.
        rr[0] = 0.f;
        float bc = beta[(size_t)(b * L + t0 + c) * NH + h];
#pragma unroll
        for (int i = 1; i < 32; i++) {
            float bi = __shfl(bc, i, 64);
            float s = -bi * rr[i];
#pragma unroll
            for (int j = 1; j < i; j++) {
                float aij = -bi * __shfl(rr[i], j, 64);
                s += aij * ((c < j) ? rr[j] : 0.f);
            }
            rr[i] = (c < i) ? s : 0.f;
        }
        if (lane < 32) {
#pragma unroll
            for (int i = 0; i < 32; i++) {
                float val = (rr[i] + ((i == c) ? 1.f : 0.f)) * bc;
                T2b[i * KTS + c] = f2bf(val);
            }
        }
    } else {
        int idx = tid - 64;
        for (int rowc = idx; rowc < 256; rowc += 192) {
            unsigned short* kT = knT + ((size_t)(bh * 64 + ch) * DK + rowc) * 32;
#pragma unroll
            for (int seg = 0; seg < 4; seg++) {
                uint4 d = *(const uint4*)&kTl[rowc * KTS + seg * 8];
                *(uint4*)(kT + seg * 8) = d;
            }
        }
    }
    __syncthreads();

    // ---- phase C: u = T2@v (f32 out), wneg = -(T2@k) (bf16 out)
#pragma unroll
    for (int mt = 0; mt < 2; mt++) {
        bf16x8 ta = *(const bf16x8*)&T2b[(mt * 16 + r16) * KTS + quad * 8];
#pragma unroll
        for (int nt2 = 0; nt2 < 4; nt2++) {
            int nt = w * 4 + nt2;
            bf16x8 vb2 = *(const bf16x8*)&vTl[(nt * 16 + r16) * KTS + quad * 8];
            bf16x8 kb = *(const bf16x8*)&kTl[(nt * 16 + r16) * KTS + quad * 8];
            f32x4 uu = MFMA16(ta, vb2, z4);
            f32x4 ww = MFMA16(ta, kb, z4);
            float* ug = u + (rowbase + mt * 16 + quad * 4) * DK + nt * 16 + r16;
            unsigned short* wg = wneg + (rowbase + mt * 16 + quad * 4) * DK + nt * 16 + r16;
#pragma unroll
            for (int r = 0; r < 4; r++) {
                ug[(size_t)r * DK] = uu[r];
                wg[(size_t)r * DK] = f2bf(-ww[r]);
            }
        }
    }
}

// ---------------- K8a: EMA local scan (bf16 v input, bf16 ema output) ----------------
// Running state s stays f32 in-register; only stored per-t samples round to bf16.
__global__ __launch_bounds__(256) void k_ema_local(const unsigned short* v, const float* gamma,
                                                   unsigned short* ema_local, float* Acum,
                                                   float* s_end, float* Pchunk)
{
    __shared__ float gsh[ET];
    int blk = blockIdx.x;
    int bh = blk >> 5;
    int ch = blk & (ENCH - 1);
    int b = bh >> 2, h = bh & 3;
    int c = threadIdx.x;
    int t0 = ch * ET;
    if (c < ET) gsh[c] = gamma[(size_t)(b * L + t0 + c) * NH + h];
    __syncthreads();
    const unsigned short* vg = v + (size_t)(b * L + t0) * D + h * DK + c;
    unsigned short* eg = ema_local + (size_t)(b * L + t0) * D + h * DK + c;
    float* Ag = Acum + (size_t)bh * L + t0;
    float s = 0.f;
    float A = 1.f;
#pragma unroll 8
    for (int i = 0; i < ET; i++) {
        float g = gsh[i];
        s = g * s + (1.f - g) * bf2f(vg[(size_t)i * D]);
        A *= g;
        eg[(size_t)i * D] = f2bf(s);
        if (c == 0) Ag[i] = A;
    }
    s_end[((size_t)bh * ENCH + ch) * DK + c] = s;
    if (c == 0) Pchunk[(size_t)bh * ENCH + ch] = A;
}

// ---------------- K8b: EMA carry scan ----------------
__global__ __launch_bounds__(256) void k_ema_carry(const float* s_end, const float* Pchunk, float* S_in)
{
    int bh = blockIdx.x;
    int c = threadIdx.x;
    float S = 0.f;
    for (int ch = 0; ch < ENCH; ch++) {
        S_in[((size_t)bh * ENCH + ch) * DK + c] = S;
        float P = Pchunk[(size_t)bh * ENCH + ch];
        S = P * S + s_end[((size_t)bh * ENCH + ch) * DK + c];
    }
}

// ---------------- K9: sequential inter-chunk scan (R1 version; od now bf16) ----------------
#define STS 280   // st row stride in shorts (dword stride 140 = 12 mod 32 -> 2-way)
#define USTR 40   // uat row stride in shorts (2-way only)
__global__ __launch_bounds__(128, 1) void k_scan(const unsigned short* qn, const unsigned short* wneg,
                                                 const unsigned short* knT, const unsigned short* attnb,
                                                 const float* u, unsigned short* od)
{
    __shared__ __align__(16) unsigned short st[16 * STS];   // S^T bf16: [c][dk]
    __shared__ __align__(16) unsigned short uat[16 * USTR]; // u_adj^T bf16: [c][t]
    int bh = blockIdx.x;
    int tile = blockIdx.y;      // 0..15, 16 cols each
    int b = bh >> 2, h = bh & 3;
    int mo = threadIdx.x >> 6, lane = threadIdx.x & 63;
    int r16 = lane & 15, quad = lane >> 4;
    int cbase = tile * 16;
    f32x4 z4 = {0.f, 0.f, 0.f, 0.f};
    f32x4 sacc[8];
#pragma unroll
    for (int a = 0; a < 8; a++) sacc[a] = z4;
    const unsigned short* qb = qn + (size_t)bh * L * DK;
    const unsigned short* wb = wneg + (size_t)bh * L * DK;
    const float* ub = u + (size_t)bh * L * DK;
    const unsigned short* kTbase = knT + (size_t)bh * 64 * DK * 32;
    const unsigned short* atbase = attnb + (size_t)bh * 64 * 1024;
    int dkb = mo * 128;   // this wave's S^T row base

    bf16x8 qf[2][8], wf[2][8];
    f32x4 au0[2];

    auto issue = [&](int ch, int par) {
        int t0 = ch * 32;
        const unsigned short* wrow = wb + (size_t)(t0 + 16 * mo + r16) * DK;
        const unsigned short* qrow = qb + (size_t)(t0 + 16 * mo + r16) * DK;
#pragma unroll
        for (int kt = 0; kt < 8; kt++) {
            qf[par][kt] = *(const bf16x8*)(qrow + kt * 32 + quad * 8);
            wf[par][kt] = *(const bf16x8*)(wrow + kt * 32 + quad * 8);
        }
        const float* up = ub + (size_t)(t0 + 16 * mo + quad * 4) * DK + cbase + r16;
        f32x4 a; a[0] = up[0]; a[1] = up[DK]; a[2] = up[2 * DK]; a[3] = up[3 * DK];
        au0[par] = a;
    };

    issue(0, 0);

    auto body = [&](int ch, int par) {
        int t0 = ch * 32;
        // (0) issue current-chunk kf/af early — consumed only at (F)
        bf16x8 af = *(const bf16x8*)(atbase + (size_t)ch * 1024 + (16 * mo + r16) * 32 + quad * 8);
        const unsigned short* kTb = kTbase + (size_t)ch * DK * 32;
        bf16x8 kf[8];
#pragma unroll
        for (int a = 0; a < 8; a++)
            kf[a] = *(const bf16x8*)(kTb + (size_t)(dkb + a * 16 + r16) * 32 + quad * 8);

        // (A) write this wave's S^T slab to LDS
#pragma unroll
        for (int a = 0; a < 8; a++) {
            uint2 p;
            p.x = f2bf(sacc[a][0]) | ((unsigned)f2bf(sacc[a][1]) << 16);
            p.y = f2bf(sacc[a][2]) | ((unsigned)f2bf(sacc[a][3]) << 16);
            *(uint2*)&st[r16 * STS + dkb + a * 16 + quad * 4] = p;
        }
        // (B) prefetch next chunk's qf/wf/au0
        if (ch + 1 < NCH) issue(ch + 1, par ^ 1);
        bar_lds();

        // (C) u_adj = u - w@S ; o_partial = q@S
        f32x4 au = au0[par], ao = z4;
#pragma unroll
        for (int kt = 0; kt < 8; kt++) {
            bf16x8 sfr = *(const bf16x8*)&st[r16 * STS + kt * 32 + quad * 8];
            au = MFMA16(wf[par][kt], sfr, au);
            ao = MFMA16(qf[par][kt], sfr, ao);
        }
        // (D) write u_adj^T
        {
            uint2 p;
            p.x = f2bf(au[0]) | ((unsigned)f2bf(au[1]) << 16);
            p.y = f2bf(au[2]) | ((unsigned)f2bf(au[3]) << 16);
            *(uint2*)&uat[r16 * USTR + 16 * mo + quad * 4] = p;
        }
        bar_lds();

        // (F) o = q@S + attn@u_adj ; store bf16 ; S^T += kT @ u_adj
        {
            bf16x8 uf = *(const bf16x8*)&uat[r16 * USTR + quad * 8];
            ao = MFMA16(af, uf, ao);
            unsigned short* op = od + (size_t)(b * L + t0 + 16 * mo + quad * 4) * D + h * DK + cbase + r16;
            op[0] = f2bf(ao[0]); op[D] = f2bf(ao[1]);
            op[2 * D] = f2bf(ao[2]); op[3 * D] = f2bf(ao[3]);
#pragma unroll
            for (int a = 0; a < 8; a++)
                sacc[a] = MFMA16(kf[a], uf, sacc[a]);
        }
    };

    for (int ch2 = 0; ch2 < NCH; ch2 += 2) {
        body(ch2, 0);
        body(ch2 + 1, 1);
    }
}

// ---------------- K10: mix + EMA fix-up + per-head RMS norm -> bf16 (od/ema inputs bf16) ----------------
__global__ __launch_bounds__(256) void k_mixrms(const unsigned short* od, const unsigned short* ema_local,
                                                const float* Acum, const float* S_in,
                                                const float* mixinp,
                                                const float* mix_bias, const float* rms_w,
                                                unsigned short* onorm)
{
    int row = blockIdx.x;       // b*L + t
    int tid = threadIdx.x;
    int h = tid >> 6, lane = tid & 63;
    int b = row >> 11, t = row & (L - 1);
    int bh = b * NH + h;
    int ch = t >> 6;            // ET = 64
    float m = sigmoidf_(mixinp[(size_t)row * NH + h] + mix_bias[h]);
    int c = tid * 4;
    float A = Acum[(size_t)bh * L + t];
    float4 sin4 = *(const float4*)(S_in + ((size_t)bh * ENCH + ch) * DK + (c & (DK - 1)));
    ushort4 o4 = *(const ushort4*)(od + (size_t)row * D + c);
    ushort4 e4 = *(const ushort4*)(ema_local + (size_t)row * D + c);
    float ox = bf2f(o4.x), oy = bf2f(o4.y), oz = bf2f(o4.z), ow = bf2f(o4.w);
    float ex = bf2f(e4.x) + A * sin4.x;
    float ey = bf2f(e4.y) + A * sin4.y;
    float ez = bf2f(e4.z) + A * sin4.z;
    float ew = bf2f(e4.w) + A * sin4.w;
    float x0 = ox + m * (ex - ox);
    float x1 = oy + m * (ey - oy);
    float x2 = oz + m * (ez - oz);
    float x3 = ow + m * (ew - ow);
    float ss = x0 * x0 + x1 * x1 + x2 * x2 + x3 * x3;
    for (int off = 32; off; off >>= 1) ss += __shfl_xor(ss, off, 64);
    float scale = rsqrtf(ss * (1.0f / 256.0f) + 1e-5f);
    float4 w = *(const float4*)(rms_w + lane * 4);
    uint2 p;
    p.x = f2bf(x0 * scale * w.x) | ((unsigned)f2bf(x1 * scale * w.y) << 16);
    p.y = f2bf(x2 * scale * w.z) | ((unsigned)f2bf(x3 * scale * w.w) << 16);
    *(uint2*)(onorm + (size_t)row * D + c) = p;
}

extern "C" void kernel_launch(void* const* d_in, const int* in_sizes, int n_in,
                              void* d_out, int out_size, void* d_ws, size_t ws_size,
                              hipStream_t stream)
{
    (void)in_sizes; (void)n_in; (void)out_size; (void)ws_size;
    const float* hidden   = (const float*)d_in[0];
    const float* Wq       = (const float*)d_in[1];
    const float* Wk       = (const float*)d_in[2];
    const float* Wv       = (const float*)d_in[3];
    const float* conv_q   = (const float*)d_in[4];
    const float* conv_k   = (const float*)d_in[5];
    const float* conv_v   = (const float*)d_in[6];
    const float* Wb       = (const float*)d_in[7];
    const float* Wdec     = (const float*)d_in[8];
    const float* Wmix     = (const float*)d_in[9];
    const float* conv_mix = (const float*)d_in[10];
    const float* mix_bias = (const float*)d_in[11];
    const float* rms_w    = (const float*)d_in[12];
    const float* Wo       = (const float*)d_in[13];
    float* out = (float*)d_out;

    char* ws = (char*)d_ws;
    size_t off = 0;
    auto alloc = [&](size_t bytes) -> char* {
        char* p = ws + off;
        off += (bytes + 255) & ~(size_t)255;
        return p;
    };
    unsigned short* wT    = (unsigned short*)alloc((size_t)4 * D * D * 2);
    unsigned short* hidB  = (unsigned short*)alloc((size_t)B * L * D * 2);
    unsigned short* xqkv  = (unsigned short*)alloc((size_t)B * L * 3 * D * 2); // slices 1,2 reused as wneg/knT
    float* beta   = (float*)alloc((size_t)B * L * NH * 4);
    float* gamma  = (float*)alloc((size_t)B * L * NH * 4);
    float* xmix   = (float*)alloc((size_t)B * L * NH * 4);
    float* mixinp = (float*)alloc((size_t)B * L * NH * 4);
    float* qbuf   = (float*)alloc((size_t)B * L * D * 4);   // ema_local (bf16, over-allocated)
    float* kbuf   = (float*)alloc((size_t)B * L * D * 4);   // od (bf16, over-allocated)
    unsigned short* vb = (unsigned short*)alloc((size_t)B * L * D * 2);  // v bf16
    float* u      = (float*)alloc((size_t)B * L * D * 4);
    unsigned short* attnb = (unsigned short*)alloc((size_t)BH * NCH * CHUNK * CHUNK * 2);
    unsigned short* onorm = (unsigned short*)alloc((size_t)B * L * D * 2);
    unsigned short* kn    = (unsigned short*)alloc((size_t)B * L * D * 2);
    unsigned short* qn    = (unsigned short*)alloc((size_t)B * L * D * 2);
    float* Acum   = (float*)alloc((size_t)BH * L * 4);
    float* s_end  = (float*)alloc((size_t)BH * ENCH * DK * 4);
    float* Pchunk = (float*)alloc((size_t)BH * ENCH * 4);
    float* S_in   = (float*)alloc((size_t)BH * ENCH * DK * 4);

    unsigned short* wneg = xqkv + (size_t)B * L * D;       // xqkv dead after k_convnorm
    unsigned short* knT  = xqkv + (size_t)2 * B * L * D;
    unsigned short* ema_local = (unsigned short*)qbuf;
    unsigned short* od  = (unsigned short*)kbuf;

    k_wT<<<dim3(32, 32, 4), 256, 0, stream>>>(Wq, Wk, Wv, Wo, wT);
    k_smallproj<<<dim3(B * L / 4), 256, 0, stream>>>(hidden, Wb, Wdec, Wmix, beta, gamma, xmix, hidB);
    k_gemm_lds<3 * D, false><<<dim3(64, 24), 256, 0, stream>>>(hidB, wT, xqkv);
    k_convnorm<<<dim3(B * L / TB), 256, 0, stream>>>(xqkv, conv_q, conv_k, conv_v, qn, kn, vb);
    k_convmix<<<dim3(B * L * NH / 256), 256, 0, stream>>>(xmix, conv_mix, mixinp);
    k_delta_pre<<<dim3(BH * NCH), 256, 0, stream>>>(qn, kn, vb, beta, wneg, knT, attnb, u);
    k_ema_local<<<dim3(BH * ENCH), 256, 0, stream>>>(vb, gamma, ema_local, Acum, s_end, Pchunk);
    k_ema_carry<<<dim3(BH), 256, 0, stream>>>(s_end, Pchunk, S_in);
    k_scan<<<dim3(16, 16), 128, 0, stream>>>(qn, wneg, knT, attnb, u, od);
    k_mixrms<<<dim3(B * L), 256, 0, stream>>>(od, ema_local, Acum, S_in, mixinp, mix_bias, rms_w, onorm);
    k_gemm_lds<D, true><<<dim3(64, 8), 256, 0, stream>>>(onorm, wT + (size_t)3 * D * D, out);
}